// Round 1
// baseline (1476.230 us; speedup 1.0000x reference)
//
#include <hip/hip_runtime.h>
#include <stdint.h>

#define N_GENE 20000
#define N_DRUG 3000
#define D_GENE 1024
#define D_DRUG 512
#define H0 256
#define H1 128
#define E_GG 600000
#define E_DD 120000
#define E_DT 150000

// ---------------- Threefry-2x32 (JAX-compatible, 20 rounds) ----------------
__host__ __device__ inline uint32_t rotl32(uint32_t x, int d) {
    return (x << d) | (x >> (32 - d));
}

__host__ __device__ inline void tf2x32(uint32_t k0, uint32_t k1, uint32_t x0, uint32_t x1,
                                       uint32_t& o0, uint32_t& o1) {
    uint32_t ks2 = k0 ^ k1 ^ 0x1BD11BDAu;
    x0 += k0; x1 += k1;
#define TFR(r) { x0 += x1; x1 = rotl32(x1, r); x1 ^= x0; }
    TFR(13) TFR(15) TFR(26) TFR(6)
    x0 += k1; x1 += ks2 + 1u;
    TFR(17) TFR(29) TFR(16) TFR(24)
    x0 += ks2; x1 += k0 + 2u;
    TFR(13) TFR(15) TFR(26) TFR(6)
    x0 += k0; x1 += k1 + 3u;
    TFR(17) TFR(29) TFR(16) TFR(24)
    x0 += k1; x1 += ks2 + 4u;
    TFR(13) TFR(15) TFR(26) TFR(6)
    x0 += ks2; x1 += k0 + 5u;
#undef TFR
    o0 = x0; o1 = x1;
}

// dropout keep mask, jax_threefry_partitionable=True semantics:
// bits(j) = w0 ^ w1 of threefry(key, (hi32(j)=0, lo32(j)=j)); u = bits>>9 |1.0f -1; keep = u < 0.8f
__global__ void gen_mask_kernel(uint8_t* __restrict__ mask, uint32_t k0, uint32_t k1, int n) {
    int j = blockIdx.x * 256 + threadIdx.x;
    if (j >= n) return;
    uint32_t a, b;
    tf2x32(k0, k1, 0u, (uint32_t)j, a, b);
    uint32_t bits = a ^ b;
    float u = __uint_as_float((bits >> 9) | 0x3F800000u) - 1.0f;
    mask[j] = (u < 0.8f) ? 1 : 0;
}

// ---------------- CSR build ----------------
__global__ void count_dst_kernel(const int* __restrict__ dst, int E, int* cnt) {
    int e = blockIdx.x * 256 + threadIdx.x;
    if (e < E) atomicAdd(&cnt[dst[e]], 1);
}

// single-block exclusive scan, n up to ~20000
__global__ void exscan_kernel(const int* __restrict__ cnt, int* __restrict__ rowptr, int n) {
    __shared__ int buf[1024];
    __shared__ int carry_s;
    int tid = threadIdx.x;
    if (tid == 0) carry_s = 0;
    __syncthreads();
    for (int base = 0; base < n; base += 1024) {
        int i = base + tid;
        int v = (i < n) ? cnt[i] : 0;
        buf[tid] = v;
        __syncthreads();
        for (int off = 1; off < 1024; off <<= 1) {
            int t = (tid >= off) ? buf[tid - off] : 0;
            __syncthreads();
            if (tid >= off) buf[tid] += t;
            __syncthreads();
        }
        int incl = buf[tid];
        int c = carry_s;
        __syncthreads();
        if (i < n) rowptr[i] = c + incl - v;
        if (tid == 1023) carry_s = c + buf[1023];
        __syncthreads();
    }
    if (tid == 0) rowptr[n] = carry_s;
}

__global__ void copy_int_kernel(const int* __restrict__ a, int* __restrict__ b, int n) {
    int i = blockIdx.x * 256 + threadIdx.x;
    if (i < n) b[i] = a[i];
}

__global__ void fill_csr_kernel(const int* __restrict__ src, const int* __restrict__ dst, int E,
                                int* pos, int* __restrict__ col) {
    int e = blockIdx.x * 256 + threadIdx.x;
    if (e < E) {
        int p = atomicAdd(&pos[dst[e]], 1);
        col[p] = src[e];
    }
}

__global__ void dinv_kernel(const int* __restrict__ cnt, float* __restrict__ dinv, int n) {
    int i = blockIdx.x * 256 + threadIdx.x;
    if (i < n) dinv[i] = 1.0f / sqrtf((float)cnt[i] + 1.0f);  // deg includes self loop
}

// ---------------- fp32 GEMM, dropout mask fused into A-load ----------------
// C[M,N] = (A .* mask * 1.25) @ B ; tiles 64x64x16, 256 threads, 4x4 microtile
#define BM 64
#define BN 64
#define BK 16
__global__ __launch_bounds__(256) void gemm_masked_kernel(
    const float* __restrict__ A, const uint8_t* __restrict__ mask,
    const float* __restrict__ B, float* __restrict__ C, int M, int K, int N) {
    __shared__ float As[BK][BM + 1];
    __shared__ float Bs[BK][BN + 1];
    int tid = threadIdx.x;
    int tx = tid & 15, ty = tid >> 4;
    int m0 = ty * 4, n0 = tx * 4;
    int gm = blockIdx.y * BM, gn = blockIdx.x * BN;
    float acc[4][4] = {};
    for (int kt = 0; kt < K; kt += BK) {
#pragma unroll
        for (int i = 0; i < 4; i++) {
            int idx = tid + 256 * i;
            int m = idx >> 4, k = idx & 15;
            int gr = gm + m;
            float v = 0.f;
            if (gr < M) {
                size_t gi = (size_t)gr * K + kt + k;
                v = A[gi] * (mask[gi] ? 1.25f : 0.f);
            }
            As[k][m] = v;
        }
#pragma unroll
        for (int i = 0; i < 4; i++) {
            int idx = tid + 256 * i;
            int k = idx >> 6, n = idx & 63;
            Bs[k][n] = B[(size_t)(kt + k) * N + gn + n];
        }
        __syncthreads();
#pragma unroll
        for (int k = 0; k < BK; k++) {
            float a[4], b[4];
#pragma unroll
            for (int i = 0; i < 4; i++) a[i] = As[k][m0 + i];
#pragma unroll
            for (int j = 0; j < 4; j++) b[j] = Bs[k][n0 + j];
#pragma unroll
            for (int i = 0; i < 4; i++)
#pragma unroll
                for (int j = 0; j < 4; j++) acc[i][j] += a[i] * b[j];
        }
        __syncthreads();
    }
#pragma unroll
    for (int i = 0; i < 4; i++) {
        int gr = gm + m0 + i;
        if (gr < M) {
#pragma unroll
            for (int j = 0; j < 4; j++) C[(size_t)gr * N + gn + n0 + j] = acc[i][j];
        }
    }
}

// ---------------- fused aggregate + bias + relu + l2norm + store/add ----------------
// one wave per dst row; F = features per lane (h = 64*F)
template <int F>
__global__ __launch_bounds__(256) void agg_kernel(
    const float* __restrict__ XW, const int* __restrict__ rowptr, const int* __restrict__ col,
    const float* __restrict__ dinv, const float* __restrict__ bias,
    float* __restrict__ out, int n_dst, int addmode) {
    const int h = 64 * F;
    int lane = threadIdx.x & 63;
    int row = blockIdx.x * 4 + (threadIdx.x >> 6);
    if (row >= n_dst) return;
    float acc[F];
#pragma unroll
    for (int i = 0; i < F; i++) acc[i] = 0.f;
    int s0 = rowptr[row], s1 = rowptr[row + 1];
    float dd = 1.f;
    if (dinv) {  // GCN-normalized variant: self loop with weight dinv[row]^2
        dd = dinv[row];
        float w = dd * dd;
        const float* xr = XW + (size_t)row * h;
#pragma unroll
        for (int i = 0; i < F; i++) acc[i] += xr[lane + 64 * i] * w;
    }
    for (int p = s0; p < s1; p++) {
        int s = col[p];
        float w = dinv ? dd * dinv[s] : 1.f;
        const float* xr = XW + (size_t)s * h;
#pragma unroll
        for (int i = 0; i < F; i++) acc[i] += xr[lane + 64 * i] * w;
    }
    float ss = 0.f;
#pragma unroll
    for (int i = 0; i < F; i++) {
        float v = acc[i] + bias[lane + 64 * i];
        v = fmaxf(v, 0.f);
        acc[i] = v;
        ss += v * v;
    }
#pragma unroll
    for (int off = 32; off >= 1; off >>= 1) ss += __shfl_xor(ss, off, 64);
    float nrm = sqrtf(ss);
    float scale = 1.0f / fmaxf(nrm, 1e-12f);
    float* orow = out + (size_t)row * h;
#pragma unroll
    for (int i = 0; i < F; i++) {
        float v = acc[i] * scale;
        if (addmode) orow[lane + 64 * i] += v;
        else orow[lane + 64 * i] = v;
    }
}

// ---------------- host ----------------
extern "C" void kernel_launch(void* const* d_in, const int* in_sizes, int n_in,
                              void* d_out, int out_size, void* d_ws, size_t ws_size,
                              hipStream_t stream) {
    const float* gene = (const float*)d_in[0];
    const float* drug = (const float*)d_in[1];
    const int* ei_gg = (const int*)d_in[2];
    const int* ei_dd = (const int*)d_in[3];
    const int* ei_dt = (const int*)d_in[4];
    const int* ei_td = (const int*)d_in[5];
    const float* W0gg = (const float*)d_in[6];  const float* b0gg = (const float*)d_in[7];
    const float* W0dd = (const float*)d_in[8];  const float* b0dd = (const float*)d_in[9];
    const float* W0dt = (const float*)d_in[10]; const float* b0dt = (const float*)d_in[11];
    const float* W0td = (const float*)d_in[12]; const float* b0td = (const float*)d_in[13];
    const float* W1gg = (const float*)d_in[14]; const float* b1gg = (const float*)d_in[15];
    const float* W1dd = (const float*)d_in[16]; const float* b1dd = (const float*)d_in[17];
    const float* W1dt = (const float*)d_in[18]; const float* b1dt = (const float*)d_in[19];
    const float* W1td = (const float*)d_in[20]; const float* b1td = (const float*)d_in[21];

    // dropout keys: dk[i] = threefry((0,42), (0,i))  (partitionable fold-like split)
    uint32_t dk[8][2];
    for (uint32_t i = 0; i < 8; i++) tf2x32(0u, 42u, 0u, i, dk[i][0], dk[i][1]);

    // workspace carve
    char* p = (char*)d_ws;
    auto take = [&](size_t bytes) -> void* {
        void* r = (void*)p;
        p += (bytes + 255) & ~(size_t)255;
        return r;
    };
    float* XW   = (float*)take(sizeof(float) * (size_t)N_GENE * H0);
    float* xg1  = (float*)take(sizeof(float) * (size_t)N_GENE * H0);
    float* xd1  = (float*)take(sizeof(float) * (size_t)N_DRUG * H0);
    uint8_t* mask = (uint8_t*)take((size_t)N_GENE * D_GENE);
    float* dinv_g = (float*)take(sizeof(float) * N_GENE);
    float* dinv_d = (float*)take(sizeof(float) * N_DRUG);
    int* cnt_gg = (int*)take(4 * N_GENE); int* rp_gg = (int*)take(4 * (N_GENE + 1));
    int* pos_gg = (int*)take(4 * N_GENE); int* col_gg = (int*)take(4 * E_GG);
    int* cnt_dd = (int*)take(4 * N_DRUG); int* rp_dd = (int*)take(4 * (N_DRUG + 1));
    int* pos_dd = (int*)take(4 * N_DRUG); int* col_dd = (int*)take(4 * E_DD);
    int* cnt_dt = (int*)take(4 * N_GENE); int* rp_dt = (int*)take(4 * (N_GENE + 1));
    int* pos_dt = (int*)take(4 * N_GENE); int* col_dt = (int*)take(4 * E_DT);
    int* cnt_td = (int*)take(4 * N_DRUG); int* rp_td = (int*)take(4 * (N_DRUG + 1));
    int* pos_td = (int*)take(4 * N_DRUG); int* col_td = (int*)take(4 * E_DT);

    // ---- build CSR for the 4 graphs (same for both layers) ----
    hipMemsetAsync(cnt_gg, 0, 4 * N_GENE, stream);
    hipMemsetAsync(cnt_dd, 0, 4 * N_DRUG, stream);
    hipMemsetAsync(cnt_dt, 0, 4 * N_GENE, stream);
    hipMemsetAsync(cnt_td, 0, 4 * N_DRUG, stream);
    count_dst_kernel<<<(E_GG + 255) / 256, 256, 0, stream>>>(ei_gg + E_GG, E_GG, cnt_gg);
    count_dst_kernel<<<(E_DD + 255) / 256, 256, 0, stream>>>(ei_dd + E_DD, E_DD, cnt_dd);
    count_dst_kernel<<<(E_DT + 255) / 256, 256, 0, stream>>>(ei_dt + E_DT, E_DT, cnt_dt);
    count_dst_kernel<<<(E_DT + 255) / 256, 256, 0, stream>>>(ei_td + E_DT, E_DT, cnt_td);
    exscan_kernel<<<1, 1024, 0, stream>>>(cnt_gg, rp_gg, N_GENE);
    exscan_kernel<<<1, 1024, 0, stream>>>(cnt_dd, rp_dd, N_DRUG);
    exscan_kernel<<<1, 1024, 0, stream>>>(cnt_dt, rp_dt, N_GENE);
    exscan_kernel<<<1, 1024, 0, stream>>>(cnt_td, rp_td, N_DRUG);
    copy_int_kernel<<<(N_GENE + 255) / 256, 256, 0, stream>>>(rp_gg, pos_gg, N_GENE);
    copy_int_kernel<<<(N_DRUG + 255) / 256, 256, 0, stream>>>(rp_dd, pos_dd, N_DRUG);
    copy_int_kernel<<<(N_GENE + 255) / 256, 256, 0, stream>>>(rp_dt, pos_dt, N_GENE);
    copy_int_kernel<<<(N_DRUG + 255) / 256, 256, 0, stream>>>(rp_td, pos_td, N_DRUG);
    fill_csr_kernel<<<(E_GG + 255) / 256, 256, 0, stream>>>(ei_gg, ei_gg + E_GG, E_GG, pos_gg, col_gg);
    fill_csr_kernel<<<(E_DD + 255) / 256, 256, 0, stream>>>(ei_dd, ei_dd + E_DD, E_DD, pos_dd, col_dd);
    fill_csr_kernel<<<(E_DT + 255) / 256, 256, 0, stream>>>(ei_dt, ei_dt + E_DT, E_DT, pos_dt, col_dt);
    fill_csr_kernel<<<(E_DT + 255) / 256, 256, 0, stream>>>(ei_td, ei_td + E_DT, E_DT, pos_td, col_td);
    dinv_kernel<<<(N_GENE + 255) / 256, 256, 0, stream>>>(cnt_gg, dinv_g, N_GENE);
    dinv_kernel<<<(N_DRUG + 255) / 256, 256, 0, stream>>>(cnt_dd, dinv_d, N_DRUG);

    // ---- one GCN conv: dropout-mask -> GEMM -> fused aggregate/bias/relu/l2norm ----
    auto run_conv = [&](const float* X, int M, int K, const float* W, const float* bias,
                        int h, const uint32_t* key, const int* rp, const int* col,
                        const float* dinvv, int n_dst, float* dest, int addmode) {
        int n = M * K;
        gen_mask_kernel<<<(n + 255) / 256, 256, 0, stream>>>(mask, key[0], key[1], n);
        dim3 g(h / BN, (M + BM - 1) / BM);
        gemm_masked_kernel<<<g, 256, 0, stream>>>(X, mask, W, XW, M, K, h);
        int blocks = (n_dst + 3) / 4;
        if (h == 256)
            agg_kernel<4><<<blocks, 256, 0, stream>>>(XW, rp, col, dinvv, bias, dest, n_dst, addmode);
        else
            agg_kernel<2><<<blocks, 256, 0, stream>>>(XW, rp, col, dinvv, bias, dest, n_dst, addmode);
    };

    // ---- layer 0 ----
    run_conv(gene, N_GENE, D_GENE, W0gg, b0gg, H0, dk[0], rp_gg, col_gg, dinv_g, N_GENE, xg1, 0);
    run_conv(drug, N_DRUG, D_DRUG, W0dt, b0dt, H0, dk[2], rp_dt, col_dt, nullptr, N_GENE, xg1, 1);
    run_conv(drug, N_DRUG, D_DRUG, W0dd, b0dd, H0, dk[1], rp_dd, col_dd, dinv_d, N_DRUG, xd1, 0);
    run_conv(gene, N_GENE, D_GENE, W0td, b0td, H0, dk[3], rp_td, col_td, nullptr, N_DRUG, xd1, 1);

    // ---- layer 1 (writes d_out directly: genes then drugs) ----
    float* og = (float*)d_out;
    float* od = og + (size_t)N_GENE * H1;
    run_conv(xg1, N_GENE, H0, W1gg, b1gg, H1, dk[4], rp_gg, col_gg, dinv_g, N_GENE, og, 0);
    run_conv(xd1, N_DRUG, H0, W1dt, b1dt, H1, dk[6], rp_dt, col_dt, nullptr, N_GENE, og, 1);
    run_conv(xd1, N_DRUG, H0, W1dd, b1dd, H1, dk[5], rp_dd, col_dd, dinv_d, N_DRUG, od, 0);
    run_conv(xg1, N_GENE, H0, W1td, b1td, H1, dk[7], rp_td, col_td, nullptr, N_DRUG, od, 1);
}

// Round 2
// 1158.569 us; speedup vs baseline: 1.2742x; 1.2742x over previous
//
#include <hip/hip_runtime.h>
#include <stdint.h>

#define N_GENE 20000
#define N_DRUG 3000
#define D_GENE 1024
#define D_DRUG 512
#define H0 256
#define H1 128
#define E_GG 600000
#define E_DD 120000
#define E_DT 150000

typedef __attribute__((ext_vector_type(8))) short bf16x8;
typedef __attribute__((ext_vector_type(4))) float f32x4;

// ---------------- Threefry-2x32 (JAX-compatible, 20 rounds) ----------------
__host__ __device__ inline uint32_t rotl32(uint32_t x, int d) {
    return (x << d) | (x >> (32 - d));
}

__host__ __device__ inline void tf2x32(uint32_t k0, uint32_t k1, uint32_t x0, uint32_t x1,
                                       uint32_t& o0, uint32_t& o1) {
    uint32_t ks2 = k0 ^ k1 ^ 0x1BD11BDAu;
    x0 += k0; x1 += k1;
#define TFR(r) { x0 += x1; x1 = rotl32(x1, r); x1 ^= x0; }
    TFR(13) TFR(15) TFR(26) TFR(6)
    x0 += k1; x1 += ks2 + 1u;
    TFR(17) TFR(29) TFR(16) TFR(24)
    x0 += ks2; x1 += k0 + 2u;
    TFR(13) TFR(15) TFR(26) TFR(6)
    x0 += k0; x1 += k1 + 3u;
    TFR(17) TFR(29) TFR(16) TFR(24)
    x0 += k1; x1 += ks2 + 4u;
    TFR(13) TFR(15) TFR(26) TFR(6)
    x0 += ks2; x1 += k0 + 5u;
#undef TFR
    o0 = x0; o1 = x1;
}

__device__ inline short f2bf(float f) {  // round-to-nearest-even bf16
    uint32_t u = __float_as_uint(f);
    uint32_t r = (u + 0x7FFFu + ((u >> 16) & 1u)) >> 16;
    return (short)r;
}

// fused dropout (partitionable threefry) + fp32->bf16 cast; 4 elems/thread
__global__ void cast_mask_kernel(const float* __restrict__ X, short* __restrict__ Y,
                                 uint32_t k0, uint32_t k1, int n) {
    int j = (blockIdx.x * 256 + threadIdx.x) * 4;
    if (j >= n) return;
    float4 x = *(const float4*)(X + j);
    short o[4];
    float xv[4] = {x.x, x.y, x.z, x.w};
#pragma unroll
    for (int i = 0; i < 4; i++) {
        uint32_t a, b;
        tf2x32(k0, k1, 0u, (uint32_t)(j + i), a, b);
        uint32_t bits = a ^ b;
        float u = __uint_as_float((bits >> 9) | 0x3F800000u) - 1.0f;
        o[i] = (u < 0.8f) ? f2bf(xv[i] * 1.25f) : (short)0;
    }
    *(short4*)(Y + j) = make_short4(o[0], o[1], o[2], o[3]);
}

// W[K,N] fp32 -> Wt[N,K] bf16
__global__ void castT_kernel(const float* __restrict__ W, short* __restrict__ Wt, int K, int N) {
    int idx = blockIdx.x * 256 + threadIdx.x;
    if (idx >= K * N) return;
    int n = idx / K, k = idx - n * K;
    Wt[idx] = f2bf(W[(size_t)k * N + n]);
}

// ---------------- MFMA bf16 GEMM ----------------
// C[M,N] = A[M,K](bf16) @ Bt[N,K](bf16)^T, fp32 accum.
// 1 wave/block, 16 rows/wave, full N per wave (NF = N/16 fragments).
template <int NF>
__global__ __launch_bounds__(64) void mfma_gemm_kernel(
    const short* __restrict__ A, const short* __restrict__ Bt,
    float* __restrict__ C, int M, int K, int N) {
    int lane = threadIdx.x;
    int m = lane & 15, kb = lane >> 4;  // A row within tile, k-block
    int row0 = blockIdx.x * 16;
    int row = row0 + m;
    bool valid = row < M;
    const short* ap = A + (size_t)(valid ? row : 0) * K + kb * 8;
    f32x4 acc[NF];
#pragma unroll
    for (int i = 0; i < NF; i++) acc[i] = (f32x4){0.f, 0.f, 0.f, 0.f};
#pragma unroll 2
    for (int k0 = 0; k0 < K; k0 += 32) {
        bf16x8 af = *(const bf16x8*)(ap + k0);
        if (!valid) af = (bf16x8)(short)0;
#pragma unroll
        for (int nf = 0; nf < NF; nf++) {
            bf16x8 bfr = *(const bf16x8*)(Bt + (size_t)(nf * 16 + m) * K + kb * 8 + k0);
            acc[nf] = __builtin_amdgcn_mfma_f32_16x16x32_bf16(af, bfr, acc[nf], 0, 0, 0);
        }
    }
    // C/D layout: col = lane&15, row = (lane>>4)*4 + j
    int r0 = row0 + kb * 4;
#pragma unroll
    for (int nf = 0; nf < NF; nf++) {
#pragma unroll
        for (int j = 0; j < 4; j++) {
            int r = r0 + j;
            if (r < M) C[(size_t)r * N + nf * 16 + m] = acc[nf][j];
        }
    }
}

// ---------------- CSR build ----------------
__global__ void count_dst_kernel(const int* __restrict__ dst, int E, int* cnt) {
    int e = blockIdx.x * 256 + threadIdx.x;
    if (e < E) atomicAdd(&cnt[dst[e]], 1);
}

__global__ void exscan_kernel(const int* __restrict__ cnt, int* __restrict__ rowptr, int n) {
    __shared__ int buf[1024];
    __shared__ int carry_s;
    int tid = threadIdx.x;
    if (tid == 0) carry_s = 0;
    __syncthreads();
    for (int base = 0; base < n; base += 1024) {
        int i = base + tid;
        int v = (i < n) ? cnt[i] : 0;
        buf[tid] = v;
        __syncthreads();
        for (int off = 1; off < 1024; off <<= 1) {
            int t = (tid >= off) ? buf[tid - off] : 0;
            __syncthreads();
            if (tid >= off) buf[tid] += t;
            __syncthreads();
        }
        int incl = buf[tid];
        int c = carry_s;
        __syncthreads();
        if (i < n) rowptr[i] = c + incl - v;
        if (tid == 1023) carry_s = c + buf[1023];
        __syncthreads();
    }
    if (tid == 0) rowptr[n] = carry_s;
}

__global__ void copy_int_kernel(const int* __restrict__ a, int* __restrict__ b, int n) {
    int i = blockIdx.x * 256 + threadIdx.x;
    if (i < n) b[i] = a[i];
}

__global__ void fill_csr_kernel(const int* __restrict__ src, const int* __restrict__ dst, int E,
                                int* pos, int* __restrict__ col) {
    int e = blockIdx.x * 256 + threadIdx.x;
    if (e < E) {
        int p = atomicAdd(&pos[dst[e]], 1);
        col[p] = src[e];
    }
}

__global__ void dinv_kernel(const int* __restrict__ cnt, float* __restrict__ dinv, int n) {
    int i = blockIdx.x * 256 + threadIdx.x;
    if (i < n) dinv[i] = 1.0f / sqrtf((float)cnt[i] + 1.0f);
}

// ---------------- fused aggregate + bias + relu + l2norm + store/add ----------------
template <int F>
__global__ __launch_bounds__(256) void agg_kernel(
    const float* __restrict__ XW, const int* __restrict__ rowptr, const int* __restrict__ col,
    const float* __restrict__ dinv, const float* __restrict__ bias,
    float* __restrict__ out, int n_dst, int addmode) {
    const int h = 64 * F;
    int lane = threadIdx.x & 63;
    int row = blockIdx.x * 4 + (threadIdx.x >> 6);
    if (row >= n_dst) return;
    float acc[F];
#pragma unroll
    for (int i = 0; i < F; i++) acc[i] = 0.f;
    int s0 = rowptr[row], s1 = rowptr[row + 1];
    float dd = 1.f;
    if (dinv) {
        dd = dinv[row];
        float w = dd * dd;
        const float* xr = XW + (size_t)row * h;
#pragma unroll
        for (int i = 0; i < F; i++) acc[i] += xr[lane + 64 * i] * w;
    }
    for (int p = s0; p < s1; p++) {
        int s = col[p];
        float w = dinv ? dd * dinv[s] : 1.f;
        const float* xr = XW + (size_t)s * h;
#pragma unroll
        for (int i = 0; i < F; i++) acc[i] += xr[lane + 64 * i] * w;
    }
    float ss = 0.f;
#pragma unroll
    for (int i = 0; i < F; i++) {
        float v = acc[i] + bias[lane + 64 * i];
        v = fmaxf(v, 0.f);
        acc[i] = v;
        ss += v * v;
    }
#pragma unroll
    for (int off = 32; off >= 1; off >>= 1) ss += __shfl_xor(ss, off, 64);
    float nrm = sqrtf(ss);
    float scale = 1.0f / fmaxf(nrm, 1e-12f);
    float* orow = out + (size_t)row * h;
#pragma unroll
    for (int i = 0; i < F; i++) {
        float v = acc[i] * scale;
        if (addmode) orow[lane + 64 * i] += v;
        else orow[lane + 64 * i] = v;
    }
}

// ---------------- host ----------------
extern "C" void kernel_launch(void* const* d_in, const int* in_sizes, int n_in,
                              void* d_out, int out_size, void* d_ws, size_t ws_size,
                              hipStream_t stream) {
    const float* gene = (const float*)d_in[0];
    const float* drug = (const float*)d_in[1];
    const int* ei_gg = (const int*)d_in[2];
    const int* ei_dd = (const int*)d_in[3];
    const int* ei_dt = (const int*)d_in[4];
    const int* ei_td = (const int*)d_in[5];
    const float* W0gg = (const float*)d_in[6];  const float* b0gg = (const float*)d_in[7];
    const float* W0dd = (const float*)d_in[8];  const float* b0dd = (const float*)d_in[9];
    const float* W0dt = (const float*)d_in[10]; const float* b0dt = (const float*)d_in[11];
    const float* W0td = (const float*)d_in[12]; const float* b0td = (const float*)d_in[13];
    const float* W1gg = (const float*)d_in[14]; const float* b1gg = (const float*)d_in[15];
    const float* W1dd = (const float*)d_in[16]; const float* b1dd = (const float*)d_in[17];
    const float* W1dt = (const float*)d_in[18]; const float* b1dt = (const float*)d_in[19];
    const float* W1td = (const float*)d_in[20]; const float* b1td = (const float*)d_in[21];

    uint32_t dk[8][2];
    for (uint32_t i = 0; i < 8; i++) tf2x32(0u, 42u, 0u, i, dk[i][0], dk[i][1]);

    char* p = (char*)d_ws;
    auto take = [&](size_t bytes) -> void* {
        void* r = (void*)p;
        p += (bytes + 255) & ~(size_t)255;
        return r;
    };
    float* XW   = (float*)take(sizeof(float) * (size_t)N_GENE * H0);
    float* xg1  = (float*)take(sizeof(float) * (size_t)N_GENE * H0);
    float* xd1  = (float*)take(sizeof(float) * (size_t)N_DRUG * H0);
    short* Am   = (short*)take(sizeof(short) * (size_t)N_GENE * D_GENE);
    short* Wt   = (short*)take(sizeof(short) * (size_t)D_GENE * H0);
    float* dinv_g = (float*)take(sizeof(float) * N_GENE);
    float* dinv_d = (float*)take(sizeof(float) * N_DRUG);
    int* cnt_gg = (int*)take(4 * N_GENE); int* rp_gg = (int*)take(4 * (N_GENE + 1));
    int* pos_gg = (int*)take(4 * N_GENE); int* col_gg = (int*)take(4 * E_GG);
    int* cnt_dd = (int*)take(4 * N_DRUG); int* rp_dd = (int*)take(4 * (N_DRUG + 1));
    int* pos_dd = (int*)take(4 * N_DRUG); int* col_dd = (int*)take(4 * E_DD);
    int* cnt_dt = (int*)take(4 * N_GENE); int* rp_dt = (int*)take(4 * (N_GENE + 1));
    int* pos_dt = (int*)take(4 * N_GENE); int* col_dt = (int*)take(4 * E_DT);
    int* cnt_td = (int*)take(4 * N_DRUG); int* rp_td = (int*)take(4 * (N_DRUG + 1));
    int* pos_td = (int*)take(4 * N_DRUG); int* col_td = (int*)take(4 * E_DT);

    // ---- CSR build (same graphs both layers) ----
    hipMemsetAsync(cnt_gg, 0, 4 * N_GENE, stream);
    hipMemsetAsync(cnt_dd, 0, 4 * N_DRUG, stream);
    hipMemsetAsync(cnt_dt, 0, 4 * N_GENE, stream);
    hipMemsetAsync(cnt_td, 0, 4 * N_DRUG, stream);
    count_dst_kernel<<<(E_GG + 255) / 256, 256, 0, stream>>>(ei_gg + E_GG, E_GG, cnt_gg);
    count_dst_kernel<<<(E_DD + 255) / 256, 256, 0, stream>>>(ei_dd + E_DD, E_DD, cnt_dd);
    count_dst_kernel<<<(E_DT + 255) / 256, 256, 0, stream>>>(ei_dt + E_DT, E_DT, cnt_dt);
    count_dst_kernel<<<(E_DT + 255) / 256, 256, 0, stream>>>(ei_td + E_DT, E_DT, cnt_td);
    exscan_kernel<<<1, 1024, 0, stream>>>(cnt_gg, rp_gg, N_GENE);
    exscan_kernel<<<1, 1024, 0, stream>>>(cnt_dd, rp_dd, N_DRUG);
    exscan_kernel<<<1, 1024, 0, stream>>>(cnt_dt, rp_dt, N_GENE);
    exscan_kernel<<<1, 1024, 0, stream>>>(cnt_td, rp_td, N_DRUG);
    copy_int_kernel<<<(N_GENE + 255) / 256, 256, 0, stream>>>(rp_gg, pos_gg, N_GENE);
    copy_int_kernel<<<(N_DRUG + 255) / 256, 256, 0, stream>>>(rp_dd, pos_dd, N_DRUG);
    copy_int_kernel<<<(N_GENE + 255) / 256, 256, 0, stream>>>(rp_dt, pos_dt, N_GENE);
    copy_int_kernel<<<(N_DRUG + 255) / 256, 256, 0, stream>>>(rp_td, pos_td, N_DRUG);
    fill_csr_kernel<<<(E_GG + 255) / 256, 256, 0, stream>>>(ei_gg, ei_gg + E_GG, E_GG, pos_gg, col_gg);
    fill_csr_kernel<<<(E_DD + 255) / 256, 256, 0, stream>>>(ei_dd, ei_dd + E_DD, E_DD, pos_dd, col_dd);
    fill_csr_kernel<<<(E_DT + 255) / 256, 256, 0, stream>>>(ei_dt, ei_dt + E_DT, E_DT, pos_dt, col_dt);
    fill_csr_kernel<<<(E_DT + 255) / 256, 256, 0, stream>>>(ei_td, ei_td + E_DT, E_DT, pos_td, col_td);
    dinv_kernel<<<(N_GENE + 255) / 256, 256, 0, stream>>>(cnt_gg, dinv_g, N_GENE);
    dinv_kernel<<<(N_DRUG + 255) / 256, 256, 0, stream>>>(cnt_dd, dinv_d, N_DRUG);

    // ---- one conv: dropout+cast -> castT(W) -> MFMA GEMM -> fused agg ----
    auto run_conv = [&](const float* X, int M, int K, const float* W, const float* bias,
                        int h, const uint32_t* key, const int* rp, const int* col,
                        const float* dinvv, int n_dst, float* dest, int addmode) {
        int n = M * K;
        cast_mask_kernel<<<(n / 4 + 255) / 256, 256, 0, stream>>>(X, Am, key[0], key[1], n);
        castT_kernel<<<(K * h + 255) / 256, 256, 0, stream>>>(W, Wt, K, h);
        int gblocks = (M + 15) / 16;
        if (h == 256)
            mfma_gemm_kernel<16><<<gblocks, 64, 0, stream>>>(Am, Wt, XW, M, K, h);
        else
            mfma_gemm_kernel<8><<<gblocks, 64, 0, stream>>>(Am, Wt, XW, M, K, h);
        int blocks = (n_dst + 3) / 4;
        if (h == 256)
            agg_kernel<4><<<blocks, 256, 0, stream>>>(XW, rp, col, dinvv, bias, dest, n_dst, addmode);
        else
            agg_kernel<2><<<blocks, 256, 0, stream>>>(XW, rp, col, dinvv, bias, dest, n_dst, addmode);
    };

    // ---- layer 0 ----
    run_conv(gene, N_GENE, D_GENE, W0gg, b0gg, H0, dk[0], rp_gg, col_gg, dinv_g, N_GENE, xg1, 0);
    run_conv(drug, N_DRUG, D_DRUG, W0dt, b0dt, H0, dk[2], rp_dt, col_dt, nullptr, N_GENE, xg1, 1);
    run_conv(drug, N_DRUG, D_DRUG, W0dd, b0dd, H0, dk[1], rp_dd, col_dd, dinv_d, N_DRUG, xd1, 0);
    run_conv(gene, N_GENE, D_GENE, W0td, b0td, H0, dk[3], rp_td, col_td, nullptr, N_DRUG, xd1, 1);

    // ---- layer 1 -> d_out (genes then drugs) ----
    float* og = (float*)d_out;
    float* od = og + (size_t)N_GENE * H1;
    run_conv(xg1, N_GENE, H0, W1gg, b1gg, H1, dk[4], rp_gg, col_gg, dinv_g, N_GENE, og, 0);
    run_conv(xd1, N_DRUG, H0, W1dt, b1dt, H1, dk[6], rp_dt, col_dt, nullptr, N_GENE, og, 1);
    run_conv(xd1, N_DRUG, H0, W1dd, b1dd, H1, dk[5], rp_dd, col_dd, dinv_d, N_DRUG, od, 0);
    run_conv(xg1, N_GENE, H0, W1td, b1td, H1, dk[7], rp_td, col_td, nullptr, N_DRUG, od, 1);
}

// Round 3
// 842.748 us; speedup vs baseline: 1.7517x; 1.3748x over previous
//
#include <hip/hip_runtime.h>
#include <stdint.h>

#define N_GENE 20000
#define N_DRUG 3000
#define D_GENE 1024
#define D_DRUG 512
#define H0 256
#define H1 128
#define E_GG 600000
#define E_DD 120000
#define E_DT 150000

typedef __attribute__((ext_vector_type(8))) short bf16x8;
typedef __attribute__((ext_vector_type(4))) float f32x4;

// ---------------- Threefry-2x32 (JAX-compatible, 20 rounds) ----------------
__host__ __device__ inline uint32_t rotl32(uint32_t x, int d) {
    return (x << d) | (x >> (32 - d));
}

__host__ __device__ inline void tf2x32(uint32_t k0, uint32_t k1, uint32_t x0, uint32_t x1,
                                       uint32_t& o0, uint32_t& o1) {
    uint32_t ks2 = k0 ^ k1 ^ 0x1BD11BDAu;
    x0 += k0; x1 += k1;
#define TFR(r) { x0 += x1; x1 = rotl32(x1, r); x1 ^= x0; }
    TFR(13) TFR(15) TFR(26) TFR(6)
    x0 += k1; x1 += ks2 + 1u;
    TFR(17) TFR(29) TFR(16) TFR(24)
    x0 += ks2; x1 += k0 + 2u;
    TFR(13) TFR(15) TFR(26) TFR(6)
    x0 += k0; x1 += k1 + 3u;
    TFR(17) TFR(29) TFR(16) TFR(24)
    x0 += k1; x1 += ks2 + 4u;
    TFR(13) TFR(15) TFR(26) TFR(6)
    x0 += ks2; x1 += k0 + 5u;
#undef TFR
    o0 = x0; o1 = x1;
}

__device__ inline short f2bf(float f) {  // round-to-nearest-even bf16
    uint32_t u = __float_as_uint(f);
    uint32_t r = (u + 0x7FFFu + ((u >> 16) & 1u)) >> 16;
    return (short)r;
}

// fused dropout (partitionable threefry) + fp32->bf16 cast; 4 elems/thread
__global__ void cast_mask_kernel(const float* __restrict__ X, short* __restrict__ Y,
                                 uint32_t k0, uint32_t k1, int n) {
    int j = (blockIdx.x * 256 + threadIdx.x) * 4;
    if (j >= n) return;
    float4 x = *(const float4*)(X + j);
    short o[4];
    float xv[4] = {x.x, x.y, x.z, x.w};
#pragma unroll
    for (int i = 0; i < 4; i++) {
        uint32_t a, b;
        tf2x32(k0, k1, 0u, (uint32_t)(j + i), a, b);
        uint32_t bits = a ^ b;
        float u = __uint_as_float((bits >> 9) | 0x3F800000u) - 1.0f;
        o[i] = (u < 0.8f) ? f2bf(xv[i] * 1.25f) : (short)0;
    }
    *(short4*)(Y + j) = make_short4(o[0], o[1], o[2], o[3]);
}

// W[K,N] fp32 -> Wt[N,K] bf16
__global__ void castT_kernel(const float* __restrict__ W, short* __restrict__ Wt, int K, int N) {
    int idx = blockIdx.x * 256 + threadIdx.x;
    if (idx >= K * N) return;
    int n = idx / K, k = idx - n * K;
    Wt[idx] = f2bf(W[(size_t)k * N + n]);
}

// ---------------- LDS-tiled MFMA bf16 GEMM ----------------
// C[M,N] = A[M,K](bf16) @ Bt[N,K](bf16)^T, fp32 accum.
// 64x64 tile, BK=64, 256 threads (4 waves 2x2, each wave 32x32).
// Reg-staged A/B tiles (T14 split: issue next loads before compute).
// LDS rows padded 64->72 shorts (144 B): 16B-aligned, bank-conflict-free-ish.
#define LDP 72
__global__ __launch_bounds__(256) void mfma_tile_kernel(
    const short* __restrict__ A, const short* __restrict__ Bt,
    float* __restrict__ C, int M, int K, int N) {
    __shared__ short As[64 * LDP];
    __shared__ short Bs[64 * LDP];
    int tid = threadIdx.x;
    int lane = tid & 63;
    int w = tid >> 6;
    int m = lane & 15, kb = lane >> 4;
    int m0w = (w >> 1) * 32, n0w = (w & 1) * 32;
    int gm = blockIdx.x * 64, gn = blockIdx.y * 64;

    // staging: 2 uint4 per thread per matrix
    int flat0 = tid, flat1 = tid + 256;
    int ar0 = flat0 >> 3, ac0 = (flat0 & 7) * 8;
    int ar1 = flat1 >> 3, ac1 = (flat1 & 7) * 8;
    int agr0 = min(gm + ar0, M - 1), agr1 = min(gm + ar1, M - 1);
    int bgr0 = gn + ar0, bgr1 = gn + ar1;
    const short* pa0 = A + (size_t)agr0 * K + ac0;
    const short* pa1 = A + (size_t)agr1 * K + ac1;
    const short* pb0 = Bt + (size_t)bgr0 * K + ac0;
    const short* pb1 = Bt + (size_t)bgr1 * K + ac1;

    f32x4 acc[2][2];
#pragma unroll
    for (int i = 0; i < 2; i++)
#pragma unroll
        for (int j = 0; j < 2; j++) acc[i][j] = (f32x4){0.f, 0.f, 0.f, 0.f};

    uint4 ra0 = *(const uint4*)pa0;
    uint4 ra1 = *(const uint4*)pa1;
    uint4 rb0 = *(const uint4*)pb0;
    uint4 rb1 = *(const uint4*)pb1;

    int nt = K >> 6;
    for (int t = 0; t < nt; ++t) {
        __syncthreads();  // previous-iteration reads done
        *(uint4*)&As[ar0 * LDP + ac0] = ra0;
        *(uint4*)&As[ar1 * LDP + ac1] = ra1;
        *(uint4*)&Bs[ar0 * LDP + ac0] = rb0;
        *(uint4*)&Bs[ar1 * LDP + ac1] = rb1;
        __syncthreads();
        if (t + 1 < nt) {  // issue next-tile loads; latency hides under compute
            int kt = (t + 1) << 6;
            ra0 = *(const uint4*)(pa0 + kt);
            ra1 = *(const uint4*)(pa1 + kt);
            rb0 = *(const uint4*)(pb0 + kt);
            rb1 = *(const uint4*)(pb1 + kt);
        }
#pragma unroll
        for (int ks = 0; ks < 2; ++ks) {
            bf16x8 a0 = *(const bf16x8*)&As[(m0w + m) * LDP + ks * 32 + kb * 8];
            bf16x8 a1 = *(const bf16x8*)&As[(m0w + 16 + m) * LDP + ks * 32 + kb * 8];
            bf16x8 b0 = *(const bf16x8*)&Bs[(n0w + m) * LDP + ks * 32 + kb * 8];
            bf16x8 b1 = *(const bf16x8*)&Bs[(n0w + 16 + m) * LDP + ks * 32 + kb * 8];
            acc[0][0] = __builtin_amdgcn_mfma_f32_16x16x32_bf16(a0, b0, acc[0][0], 0, 0, 0);
            acc[0][1] = __builtin_amdgcn_mfma_f32_16x16x32_bf16(a0, b1, acc[0][1], 0, 0, 0);
            acc[1][0] = __builtin_amdgcn_mfma_f32_16x16x32_bf16(a1, b0, acc[1][0], 0, 0, 0);
            acc[1][1] = __builtin_amdgcn_mfma_f32_16x16x32_bf16(a1, b1, acc[1][1], 0, 0, 0);
        }
    }
    // C/D layout: col = lane&15, row = (lane>>4)*4 + j
#pragma unroll
    for (int mf = 0; mf < 2; ++mf)
#pragma unroll
        for (int nf = 0; nf < 2; ++nf)
#pragma unroll
            for (int j = 0; j < 4; ++j) {
                int r = gm + m0w + mf * 16 + kb * 4 + j;
                if (r < M) C[(size_t)r * N + gn + n0w + nf * 16 + m] = acc[mf][nf][j];
            }
}

// ---------------- CSR build ----------------
__global__ void count_dst_kernel(const int* __restrict__ dst, int E, int* cnt) {
    int e = blockIdx.x * 256 + threadIdx.x;
    if (e < E) atomicAdd(&cnt[dst[e]], 1);
}

__global__ void exscan_kernel(const int* __restrict__ cnt, int* __restrict__ rowptr, int n) {
    __shared__ int buf[1024];
    __shared__ int carry_s;
    int tid = threadIdx.x;
    if (tid == 0) carry_s = 0;
    __syncthreads();
    for (int base = 0; base < n; base += 1024) {
        int i = base + tid;
        int v = (i < n) ? cnt[i] : 0;
        buf[tid] = v;
        __syncthreads();
        for (int off = 1; off < 1024; off <<= 1) {
            int t = (tid >= off) ? buf[tid - off] : 0;
            __syncthreads();
            if (tid >= off) buf[tid] += t;
            __syncthreads();
        }
        int incl = buf[tid];
        int c = carry_s;
        __syncthreads();
        if (i < n) rowptr[i] = c + incl - v;
        if (tid == 1023) carry_s = c + buf[1023];
        __syncthreads();
    }
    if (tid == 0) rowptr[n] = carry_s;
}

__global__ void copy_int_kernel(const int* __restrict__ a, int* __restrict__ b, int n) {
    int i = blockIdx.x * 256 + threadIdx.x;
    if (i < n) b[i] = a[i];
}

__global__ void fill_csr_kernel(const int* __restrict__ src, const int* __restrict__ dst, int E,
                                int* pos, int* __restrict__ col) {
    int e = blockIdx.x * 256 + threadIdx.x;
    if (e < E) {
        int p = atomicAdd(&pos[dst[e]], 1);
        col[p] = src[e];
    }
}

__global__ void dinv_kernel(const int* __restrict__ cnt, float* __restrict__ dinv, int n) {
    int i = blockIdx.x * 256 + threadIdx.x;
    if (i < n) dinv[i] = 1.0f / sqrtf((float)cnt[i] + 1.0f);
}

// ---------------- fused aggregate + bias + relu + l2norm + store/add ----------------
template <int F>
__global__ __launch_bounds__(256) void agg_kernel(
    const float* __restrict__ XW, const int* __restrict__ rowptr, const int* __restrict__ col,
    const float* __restrict__ dinv, const float* __restrict__ bias,
    float* __restrict__ out, int n_dst, int addmode) {
    const int h = 64 * F;
    int lane = threadIdx.x & 63;
    int row = blockIdx.x * 4 + (threadIdx.x >> 6);
    if (row >= n_dst) return;
    float acc[F];
#pragma unroll
    for (int i = 0; i < F; i++) acc[i] = 0.f;
    int s0 = rowptr[row], s1 = rowptr[row + 1];
    float dd = 1.f;
    if (dinv) {
        dd = dinv[row];
        float w = dd * dd;
        const float* xr = XW + (size_t)row * h;
#pragma unroll
        for (int i = 0; i < F; i++) acc[i] += xr[lane + 64 * i] * w;
    }
    for (int p = s0; p < s1; p++) {
        int s = col[p];
        float w = dinv ? dd * dinv[s] : 1.f;
        const float* xr = XW + (size_t)s * h;
#pragma unroll
        for (int i = 0; i < F; i++) acc[i] += xr[lane + 64 * i] * w;
    }
    float ss = 0.f;
#pragma unroll
    for (int i = 0; i < F; i++) {
        float v = acc[i] + bias[lane + 64 * i];
        v = fmaxf(v, 0.f);
        acc[i] = v;
        ss += v * v;
    }
#pragma unroll
    for (int off = 32; off >= 1; off >>= 1) ss += __shfl_xor(ss, off, 64);
    float nrm = sqrtf(ss);
    float scale = 1.0f / fmaxf(nrm, 1e-12f);
    float* orow = out + (size_t)row * h;
#pragma unroll
    for (int i = 0; i < F; i++) {
        float v = acc[i] * scale;
        if (addmode) orow[lane + 64 * i] += v;
        else orow[lane + 64 * i] = v;
    }
}

// ---------------- host ----------------
extern "C" void kernel_launch(void* const* d_in, const int* in_sizes, int n_in,
                              void* d_out, int out_size, void* d_ws, size_t ws_size,
                              hipStream_t stream) {
    const float* gene = (const float*)d_in[0];
    const float* drug = (const float*)d_in[1];
    const int* ei_gg = (const int*)d_in[2];
    const int* ei_dd = (const int*)d_in[3];
    const int* ei_dt = (const int*)d_in[4];
    const int* ei_td = (const int*)d_in[5];
    const float* W0gg = (const float*)d_in[6];  const float* b0gg = (const float*)d_in[7];
    const float* W0dd = (const float*)d_in[8];  const float* b0dd = (const float*)d_in[9];
    const float* W0dt = (const float*)d_in[10]; const float* b0dt = (const float*)d_in[11];
    const float* W0td = (const float*)d_in[12]; const float* b0td = (const float*)d_in[13];
    const float* W1gg = (const float*)d_in[14]; const float* b1gg = (const float*)d_in[15];
    const float* W1dd = (const float*)d_in[16]; const float* b1dd = (const float*)d_in[17];
    const float* W1dt = (const float*)d_in[18]; const float* b1dt = (const float*)d_in[19];
    const float* W1td = (const float*)d_in[20]; const float* b1td = (const float*)d_in[21];

    uint32_t dk[8][2];
    for (uint32_t i = 0; i < 8; i++) tf2x32(0u, 42u, 0u, i, dk[i][0], dk[i][1]);

    char* p = (char*)d_ws;
    auto take = [&](size_t bytes) -> void* {
        void* r = (void*)p;
        p += (bytes + 255) & ~(size_t)255;
        return r;
    };
    float* XW   = (float*)take(sizeof(float) * (size_t)N_GENE * H0);
    float* xg1  = (float*)take(sizeof(float) * (size_t)N_GENE * H0);
    float* xd1  = (float*)take(sizeof(float) * (size_t)N_DRUG * H0);
    short* Am   = (short*)take(sizeof(short) * (size_t)N_GENE * D_GENE);
    short* Wt   = (short*)take(sizeof(short) * (size_t)D_GENE * H0);
    float* dinv_g = (float*)take(sizeof(float) * N_GENE);
    float* dinv_d = (float*)take(sizeof(float) * N_DRUG);
    int* cnt_gg = (int*)take(4 * N_GENE); int* rp_gg = (int*)take(4 * (N_GENE + 1));
    int* pos_gg = (int*)take(4 * N_GENE); int* col_gg = (int*)take(4 * E_GG);
    int* cnt_dd = (int*)take(4 * N_DRUG); int* rp_dd = (int*)take(4 * (N_DRUG + 1));
    int* pos_dd = (int*)take(4 * N_DRUG); int* col_dd = (int*)take(4 * E_DD);
    int* cnt_dt = (int*)take(4 * N_GENE); int* rp_dt = (int*)take(4 * (N_GENE + 1));
    int* pos_dt = (int*)take(4 * N_GENE); int* col_dt = (int*)take(4 * E_DT);
    int* cnt_td = (int*)take(4 * N_DRUG); int* rp_td = (int*)take(4 * (N_DRUG + 1));
    int* pos_td = (int*)take(4 * N_DRUG); int* col_td = (int*)take(4 * E_DT);

    // ---- CSR build (same graphs both layers) ----
    hipMemsetAsync(cnt_gg, 0, 4 * N_GENE, stream);
    hipMemsetAsync(cnt_dd, 0, 4 * N_DRUG, stream);
    hipMemsetAsync(cnt_dt, 0, 4 * N_GENE, stream);
    hipMemsetAsync(cnt_td, 0, 4 * N_DRUG, stream);
    count_dst_kernel<<<(E_GG + 255) / 256, 256, 0, stream>>>(ei_gg + E_GG, E_GG, cnt_gg);
    count_dst_kernel<<<(E_DD + 255) / 256, 256, 0, stream>>>(ei_dd + E_DD, E_DD, cnt_dd);
    count_dst_kernel<<<(E_DT + 255) / 256, 256, 0, stream>>>(ei_dt + E_DT, E_DT, cnt_dt);
    count_dst_kernel<<<(E_DT + 255) / 256, 256, 0, stream>>>(ei_td + E_DT, E_DT, cnt_td);
    exscan_kernel<<<1, 1024, 0, stream>>>(cnt_gg, rp_gg, N_GENE);
    exscan_kernel<<<1, 1024, 0, stream>>>(cnt_dd, rp_dd, N_DRUG);
    exscan_kernel<<<1, 1024, 0, stream>>>(cnt_dt, rp_dt, N_GENE);
    exscan_kernel<<<1, 1024, 0, stream>>>(cnt_td, rp_td, N_DRUG);
    copy_int_kernel<<<(N_GENE + 255) / 256, 256, 0, stream>>>(rp_gg, pos_gg, N_GENE);
    copy_int_kernel<<<(N_DRUG + 255) / 256, 256, 0, stream>>>(rp_dd, pos_dd, N_DRUG);
    copy_int_kernel<<<(N_GENE + 255) / 256, 256, 0, stream>>>(rp_dt, pos_dt, N_GENE);
    copy_int_kernel<<<(N_DRUG + 255) / 256, 256, 0, stream>>>(rp_td, pos_td, N_DRUG);
    fill_csr_kernel<<<(E_GG + 255) / 256, 256, 0, stream>>>(ei_gg, ei_gg + E_GG, E_GG, pos_gg, col_gg);
    fill_csr_kernel<<<(E_DD + 255) / 256, 256, 0, stream>>>(ei_dd, ei_dd + E_DD, E_DD, pos_dd, col_dd);
    fill_csr_kernel<<<(E_DT + 255) / 256, 256, 0, stream>>>(ei_dt, ei_dt + E_DT, E_DT, pos_dt, col_dt);
    fill_csr_kernel<<<(E_DT + 255) / 256, 256, 0, stream>>>(ei_td, ei_td + E_DT, E_DT, pos_td, col_td);
    dinv_kernel<<<(N_GENE + 255) / 256, 256, 0, stream>>>(cnt_gg, dinv_g, N_GENE);
    dinv_kernel<<<(N_DRUG + 255) / 256, 256, 0, stream>>>(cnt_dd, dinv_d, N_DRUG);

    // ---- one conv: dropout+cast -> castT(W) -> tiled MFMA GEMM -> fused agg ----
    auto run_conv = [&](const float* X, int M, int K, const float* W, const float* bias,
                        int h, const uint32_t* key, const int* rp, const int* col,
                        const float* dinvv, int n_dst, float* dest, int addmode) {
        int n = M * K;
        cast_mask_kernel<<<(n / 4 + 255) / 256, 256, 0, stream>>>(X, Am, key[0], key[1], n);
        castT_kernel<<<(K * h + 255) / 256, 256, 0, stream>>>(W, Wt, K, h);
        dim3 g((M + 63) / 64, h / 64);
        mfma_tile_kernel<<<g, 256, 0, stream>>>(Am, Wt, XW, M, K, h);
        int blocks = (n_dst + 3) / 4;
        if (h == 256)
            agg_kernel<4><<<blocks, 256, 0, stream>>>(XW, rp, col, dinvv, bias, dest, n_dst, addmode);
        else
            agg_kernel<2><<<blocks, 256, 0, stream>>>(XW, rp, col, dinvv, bias, dest, n_dst, addmode);
    };

    // ---- layer 0 ----
    run_conv(gene, N_GENE, D_GENE, W0gg, b0gg, H0, dk[0], rp_gg, col_gg, dinv_g, N_GENE, xg1, 0);
    run_conv(drug, N_DRUG, D_DRUG, W0dt, b0dt, H0, dk[2], rp_dt, col_dt, nullptr, N_GENE, xg1, 1);
    run_conv(drug, N_DRUG, D_DRUG, W0dd, b0dd, H0, dk[1], rp_dd, col_dd, dinv_d, N_DRUG, xd1, 0);
    run_conv(gene, N_GENE, D_GENE, W0td, b0td, H0, dk[3], rp_td, col_td, nullptr, N_DRUG, xd1, 1);

    // ---- layer 1 -> d_out (genes then drugs) ----
    float* og = (float*)d_out;
    float* od = og + (size_t)N_GENE * H1;
    run_conv(xg1, N_GENE, H0, W1gg, b1gg, H1, dk[4], rp_gg, col_gg, dinv_g, N_GENE, og, 0);
    run_conv(xd1, N_DRUG, H0, W1dt, b1dt, H1, dk[6], rp_dt, col_dt, nullptr, N_GENE, og, 1);
    run_conv(xd1, N_DRUG, H0, W1dd, b1dd, H1, dk[5], rp_dd, col_dd, dinv_d, N_DRUG, od, 0);
    run_conv(xg1, N_GENE, H0, W1td, b1td, H1, dk[7], rp_td, col_td, nullptr, N_DRUG, od, 1);
}

// Round 4
// 735.278 us; speedup vs baseline: 2.0077x; 1.1462x over previous
//
#include <hip/hip_runtime.h>
#include <stdint.h>

#define N_GENE 20000
#define N_DRUG 3000
#define D_GENE 1024
#define D_DRUG 512
#define H0 256
#define H1 128
#define E_GG 600000
#define E_DD 120000
#define E_DT 150000

typedef __attribute__((ext_vector_type(8))) short bf16x8;
typedef __attribute__((ext_vector_type(4))) float f32x4;

// ---------------- Threefry-2x32 (JAX-compatible, 20 rounds) ----------------
__host__ __device__ inline uint32_t rotl32(uint32_t x, int d) {
    return (x << d) | (x >> (32 - d));
}

__host__ __device__ inline void tf2x32(uint32_t k0, uint32_t k1, uint32_t x0, uint32_t x1,
                                       uint32_t& o0, uint32_t& o1) {
    uint32_t ks2 = k0 ^ k1 ^ 0x1BD11BDAu;
    x0 += k0; x1 += k1;
#define TFR(r) { x0 += x1; x1 = rotl32(x1, r); x1 ^= x0; }
    TFR(13) TFR(15) TFR(26) TFR(6)
    x0 += k1; x1 += ks2 + 1u;
    TFR(17) TFR(29) TFR(16) TFR(24)
    x0 += ks2; x1 += k0 + 2u;
    TFR(13) TFR(15) TFR(26) TFR(6)
    x0 += k0; x1 += k1 + 3u;
    TFR(17) TFR(29) TFR(16) TFR(24)
    x0 += k1; x1 += ks2 + 4u;
    TFR(13) TFR(15) TFR(26) TFR(6)
    x0 += ks2; x1 += k0 + 5u;
#undef TFR
    o0 = x0; o1 = x1;
}

__device__ inline short f2bf(float f) {  // round-to-nearest-even bf16
    uint32_t u = __float_as_uint(f);
    uint32_t r = (u + 0x7FFFu + ((u >> 16) & 1u)) >> 16;
    return (short)r;
}
__device__ inline float bf_lo(uint32_t u) { return __uint_as_float(u << 16); }
__device__ inline float bf_hi(uint32_t u) { return __uint_as_float(u & 0xFFFF0000u); }

// fused dropout (partitionable threefry) + fp32->bf16 cast; 4 elems/thread
__global__ void cast_mask_kernel(const float* __restrict__ X, short* __restrict__ Y,
                                 uint32_t k0, uint32_t k1, int n) {
    int j = (blockIdx.x * 256 + threadIdx.x) * 4;
    if (j >= n) return;
    float4 x = *(const float4*)(X + j);
    short o[4];
    float xv[4] = {x.x, x.y, x.z, x.w};
#pragma unroll
    for (int i = 0; i < 4; i++) {
        uint32_t a, b;
        tf2x32(k0, k1, 0u, (uint32_t)(j + i), a, b);
        uint32_t bits = a ^ b;
        float u = __uint_as_float((bits >> 9) | 0x3F800000u) - 1.0f;
        o[i] = (u < 0.8f) ? f2bf(xv[i] * 1.25f) : (short)0;
    }
    *(short4*)(Y + j) = make_short4(o[0], o[1], o[2], o[3]);
}

// W[K,N] fp32 -> Wt[N,K] bf16
__global__ void castT_kernel(const float* __restrict__ W, short* __restrict__ Wt, int K, int N) {
    int idx = blockIdx.x * 256 + threadIdx.x;
    if (idx >= K * N) return;
    int n = idx / K, k = idx - n * K;
    Wt[idx] = f2bf(W[(size_t)k * N + n]);
}

// ---------------- LDS-tiled MFMA bf16 GEMM, bf16 output ----------------
// C[M,N](bf16) = A[M,K](bf16) @ Bt[N,K](bf16)^T, fp32 accum.
#define LDP 72
__global__ __launch_bounds__(256) void mfma_tile_kernel(
    const short* __restrict__ A, const short* __restrict__ Bt,
    short* __restrict__ C, int M, int K, int N) {
    __shared__ short As[64 * LDP];
    __shared__ short Bs[64 * LDP];
    int tid = threadIdx.x;
    int lane = tid & 63;
    int w = tid >> 6;
    int m = lane & 15, kb = lane >> 4;
    int m0w = (w >> 1) * 32, n0w = (w & 1) * 32;
    int gm = blockIdx.x * 64, gn = blockIdx.y * 64;

    int flat0 = tid, flat1 = tid + 256;
    int ar0 = flat0 >> 3, ac0 = (flat0 & 7) * 8;
    int ar1 = flat1 >> 3, ac1 = (flat1 & 7) * 8;
    int agr0 = min(gm + ar0, M - 1), agr1 = min(gm + ar1, M - 1);
    const short* pa0 = A + (size_t)agr0 * K + ac0;
    const short* pa1 = A + (size_t)agr1 * K + ac1;
    const short* pb0 = Bt + (size_t)(gn + ar0) * K + ac0;
    const short* pb1 = Bt + (size_t)(gn + ar1) * K + ac1;

    f32x4 acc[2][2];
#pragma unroll
    for (int i = 0; i < 2; i++)
#pragma unroll
        for (int j = 0; j < 2; j++) acc[i][j] = (f32x4){0.f, 0.f, 0.f, 0.f};

    uint4 ra0 = *(const uint4*)pa0;
    uint4 ra1 = *(const uint4*)pa1;
    uint4 rb0 = *(const uint4*)pb0;
    uint4 rb1 = *(const uint4*)pb1;

    int nt = K >> 6;
    for (int t = 0; t < nt; ++t) {
        __syncthreads();
        *(uint4*)&As[ar0 * LDP + ac0] = ra0;
        *(uint4*)&As[ar1 * LDP + ac1] = ra1;
        *(uint4*)&Bs[ar0 * LDP + ac0] = rb0;
        *(uint4*)&Bs[ar1 * LDP + ac1] = rb1;
        __syncthreads();
        if (t + 1 < nt) {
            int kt = (t + 1) << 6;
            ra0 = *(const uint4*)(pa0 + kt);
            ra1 = *(const uint4*)(pa1 + kt);
            rb0 = *(const uint4*)(pb0 + kt);
            rb1 = *(const uint4*)(pb1 + kt);
        }
#pragma unroll
        for (int ks = 0; ks < 2; ++ks) {
            bf16x8 a0 = *(const bf16x8*)&As[(m0w + m) * LDP + ks * 32 + kb * 8];
            bf16x8 a1 = *(const bf16x8*)&As[(m0w + 16 + m) * LDP + ks * 32 + kb * 8];
            bf16x8 b0 = *(const bf16x8*)&Bs[(n0w + m) * LDP + ks * 32 + kb * 8];
            bf16x8 b1 = *(const bf16x8*)&Bs[(n0w + 16 + m) * LDP + ks * 32 + kb * 8];
            acc[0][0] = __builtin_amdgcn_mfma_f32_16x16x32_bf16(a0, b0, acc[0][0], 0, 0, 0);
            acc[0][1] = __builtin_amdgcn_mfma_f32_16x16x32_bf16(a0, b1, acc[0][1], 0, 0, 0);
            acc[1][0] = __builtin_amdgcn_mfma_f32_16x16x32_bf16(a1, b0, acc[1][0], 0, 0, 0);
            acc[1][1] = __builtin_amdgcn_mfma_f32_16x16x32_bf16(a1, b1, acc[1][1], 0, 0, 0);
        }
    }
    // C/D layout: col = lane&15 (=m), row = kb*4 + j
#pragma unroll
    for (int mf = 0; mf < 2; ++mf)
#pragma unroll
        for (int nf = 0; nf < 2; ++nf)
#pragma unroll
            for (int j = 0; j < 4; ++j) {
                int r = gm + m0w + mf * 16 + kb * 4 + j;
                if (r < M) C[(size_t)r * N + gn + n0w + nf * 16 + m] = f2bf(acc[mf][nf][j]);
            }
}

// ---------------- CSR build ----------------
__global__ void count_dst_kernel(const int* __restrict__ dst, int E, int* cnt) {
    int e = blockIdx.x * 256 + threadIdx.x;
    if (e < E) atomicAdd(&cnt[dst[e]], 1);
}

__global__ void exscan_kernel(const int* __restrict__ cnt, int* __restrict__ rowptr, int n) {
    __shared__ int buf[1024];
    __shared__ int carry_s;
    int tid = threadIdx.x;
    if (tid == 0) carry_s = 0;
    __syncthreads();
    for (int base = 0; base < n; base += 1024) {
        int i = base + tid;
        int v = (i < n) ? cnt[i] : 0;
        buf[tid] = v;
        __syncthreads();
        for (int off = 1; off < 1024; off <<= 1) {
            int t = (tid >= off) ? buf[tid - off] : 0;
            __syncthreads();
            if (tid >= off) buf[tid] += t;
            __syncthreads();
        }
        int incl = buf[tid];
        int c = carry_s;
        __syncthreads();
        if (i < n) rowptr[i] = c + incl - v;
        if (tid == 1023) carry_s = c + buf[1023];
        __syncthreads();
    }
    if (tid == 0) rowptr[n] = carry_s;
}

__global__ void copy_int_kernel(const int* __restrict__ a, int* __restrict__ b, int n) {
    int i = blockIdx.x * 256 + threadIdx.x;
    if (i < n) b[i] = a[i];
}

__global__ void fill_csr_kernel(const int* __restrict__ src, const int* __restrict__ dst, int E,
                                int* pos, int* __restrict__ col) {
    int e = blockIdx.x * 256 + threadIdx.x;
    if (e < E) {
        int p = atomicAdd(&pos[dst[e]], 1);
        col[p] = src[e];
    }
}

__global__ void dinv_kernel(const int* __restrict__ cnt, float* __restrict__ dinv, int n) {
    int i = blockIdx.x * 256 + threadIdx.x;
    if (i < n) dinv[i] = 1.0f / sqrtf((float)cnt[i] + 1.0f);
}

// ---------------- fused aggregate (bf16 gather) + bias + relu + l2norm ----------------
// lane owns features [lane*F, lane*F+F); F=4 -> uint2 gather, F=2 -> uint gather.
template <int F>
__global__ __launch_bounds__(256) void agg_kernel(
    const short* __restrict__ XWb, const int* __restrict__ rowptr, const int* __restrict__ col,
    const float* __restrict__ dinv, const float* __restrict__ bias,
    float* __restrict__ out, int n_dst, int addmode) {
    const int h = 64 * F;
    int lane = threadIdx.x & 63;
    int row = blockIdx.x * 4 + (threadIdx.x >> 6);
    if (row >= n_dst) return;
    int c0 = lane * F;
    float acc[F];
#pragma unroll
    for (int i = 0; i < F; i++) acc[i] = 0.f;

    int s0 = rowptr[row], s1 = rowptr[row + 1];
    float dd = 1.f;
    if (dinv) {  // self loop, weight dinv[row]^2
        dd = dinv[row];
        float w = dd * dd;
        const short* xr = XWb + (size_t)row * h + c0;
        if constexpr (F == 4) {
            uint2 u = *(const uint2*)xr;
            acc[0] += bf_lo(u.x) * w; acc[1] += bf_hi(u.x) * w;
            acc[2] += bf_lo(u.y) * w; acc[3] += bf_hi(u.y) * w;
        } else {
            uint32_t u = *(const uint32_t*)xr;
            acc[0] += bf_lo(u) * w; acc[1] += bf_hi(u) * w;
        }
    }
    int p = s0;
    for (; p + 2 <= s1; p += 2) {  // 2-edge unroll: more loads in flight
        int sA = col[p], sB = col[p + 1];
        float wA = dinv ? dd * dinv[sA] : 1.f;
        float wB = dinv ? dd * dinv[sB] : 1.f;
        if constexpr (F == 4) {
            uint2 uA = *(const uint2*)(XWb + (size_t)sA * h + c0);
            uint2 uB = *(const uint2*)(XWb + (size_t)sB * h + c0);
            acc[0] += bf_lo(uA.x) * wA; acc[1] += bf_hi(uA.x) * wA;
            acc[2] += bf_lo(uA.y) * wA; acc[3] += bf_hi(uA.y) * wA;
            acc[0] += bf_lo(uB.x) * wB; acc[1] += bf_hi(uB.x) * wB;
            acc[2] += bf_lo(uB.y) * wB; acc[3] += bf_hi(uB.y) * wB;
        } else {
            uint32_t uA = *(const uint32_t*)(XWb + (size_t)sA * h + c0);
            uint32_t uB = *(const uint32_t*)(XWb + (size_t)sB * h + c0);
            acc[0] += bf_lo(uA) * wA; acc[1] += bf_hi(uA) * wA;
            acc[0] += bf_lo(uB) * wB; acc[1] += bf_hi(uB) * wB;
        }
    }
    if (p < s1) {
        int s = col[p];
        float w = dinv ? dd * dinv[s] : 1.f;
        if constexpr (F == 4) {
            uint2 u = *(const uint2*)(XWb + (size_t)s * h + c0);
            acc[0] += bf_lo(u.x) * w; acc[1] += bf_hi(u.x) * w;
            acc[2] += bf_lo(u.y) * w; acc[3] += bf_hi(u.y) * w;
        } else {
            uint32_t u = *(const uint32_t*)(XWb + (size_t)s * h + c0);
            acc[0] += bf_lo(u) * w; acc[1] += bf_hi(u) * w;
        }
    }

    float ss = 0.f;
#pragma unroll
    for (int i = 0; i < F; i++) {
        float v = acc[i] + bias[c0 + i];
        v = fmaxf(v, 0.f);
        acc[i] = v;
        ss += v * v;
    }
#pragma unroll
    for (int off = 32; off >= 1; off >>= 1) ss += __shfl_xor(ss, off, 64);
    float scale = 1.0f / fmaxf(sqrtf(ss), 1e-12f);
    float* orow = out + (size_t)row * h + c0;
    if constexpr (F == 4) {
        float4 st = make_float4(acc[0] * scale, acc[1] * scale, acc[2] * scale, acc[3] * scale);
        if (addmode) {
            float4 old = *(const float4*)orow;
            st.x += old.x; st.y += old.y; st.z += old.z; st.w += old.w;
        }
        *(float4*)orow = st;
    } else {
        float2 st = make_float2(acc[0] * scale, acc[1] * scale);
        if (addmode) {
            float2 old = *(const float2*)orow;
            st.x += old.x; st.y += old.y;
        }
        *(float2*)orow = st;
    }
}

// ---------------- host ----------------
extern "C" void kernel_launch(void* const* d_in, const int* in_sizes, int n_in,
                              void* d_out, int out_size, void* d_ws, size_t ws_size,
                              hipStream_t stream) {
    const float* gene = (const float*)d_in[0];
    const float* drug = (const float*)d_in[1];
    const int* ei_gg = (const int*)d_in[2];
    const int* ei_dd = (const int*)d_in[3];
    const int* ei_dt = (const int*)d_in[4];
    const int* ei_td = (const int*)d_in[5];
    const float* W0gg = (const float*)d_in[6];  const float* b0gg = (const float*)d_in[7];
    const float* W0dd = (const float*)d_in[8];  const float* b0dd = (const float*)d_in[9];
    const float* W0dt = (const float*)d_in[10]; const float* b0dt = (const float*)d_in[11];
    const float* W0td = (const float*)d_in[12]; const float* b0td = (const float*)d_in[13];
    const float* W1gg = (const float*)d_in[14]; const float* b1gg = (const float*)d_in[15];
    const float* W1dd = (const float*)d_in[16]; const float* b1dd = (const float*)d_in[17];
    const float* W1dt = (const float*)d_in[18]; const float* b1dt = (const float*)d_in[19];
    const float* W1td = (const float*)d_in[20]; const float* b1td = (const float*)d_in[21];

    uint32_t dk[8][2];
    for (uint32_t i = 0; i < 8; i++) tf2x32(0u, 42u, 0u, i, dk[i][0], dk[i][1]);

    char* p = (char*)d_ws;
    auto take = [&](size_t bytes) -> void* {
        void* r = (void*)p;
        p += (bytes + 255) & ~(size_t)255;
        return r;
    };
    short* XWb  = (short*)take(sizeof(short) * (size_t)N_GENE * H0);
    float* xg1  = (float*)take(sizeof(float) * (size_t)N_GENE * H0);
    float* xd1  = (float*)take(sizeof(float) * (size_t)N_DRUG * H0);
    short* Am   = (short*)take(sizeof(short) * (size_t)N_GENE * D_GENE);
    short* Wt   = (short*)take(sizeof(short) * (size_t)D_GENE * H0);
    float* dinv_g = (float*)take(sizeof(float) * N_GENE);
    float* dinv_d = (float*)take(sizeof(float) * N_DRUG);
    int* cnt_gg = (int*)take(4 * N_GENE); int* rp_gg = (int*)take(4 * (N_GENE + 1));
    int* pos_gg = (int*)take(4 * N_GENE); int* col_gg = (int*)take(4 * E_GG);
    int* cnt_dd = (int*)take(4 * N_DRUG); int* rp_dd = (int*)take(4 * (N_DRUG + 1));
    int* pos_dd = (int*)take(4 * N_DRUG); int* col_dd = (int*)take(4 * E_DD);
    int* cnt_dt = (int*)take(4 * N_GENE); int* rp_dt = (int*)take(4 * (N_GENE + 1));
    int* pos_dt = (int*)take(4 * N_GENE); int* col_dt = (int*)take(4 * E_DT);
    int* cnt_td = (int*)take(4 * N_DRUG); int* rp_td = (int*)take(4 * (N_DRUG + 1));
    int* pos_td = (int*)take(4 * N_DRUG); int* col_td = (int*)take(4 * E_DT);

    // ---- CSR build (same graphs both layers) ----
    hipMemsetAsync(cnt_gg, 0, 4 * N_GENE, stream);
    hipMemsetAsync(cnt_dd, 0, 4 * N_DRUG, stream);
    hipMemsetAsync(cnt_dt, 0, 4 * N_GENE, stream);
    hipMemsetAsync(cnt_td, 0, 4 * N_DRUG, stream);
    count_dst_kernel<<<(E_GG + 255) / 256, 256, 0, stream>>>(ei_gg + E_GG, E_GG, cnt_gg);
    count_dst_kernel<<<(E_DD + 255) / 256, 256, 0, stream>>>(ei_dd + E_DD, E_DD, cnt_dd);
    count_dst_kernel<<<(E_DT + 255) / 256, 256, 0, stream>>>(ei_dt + E_DT, E_DT, cnt_dt);
    count_dst_kernel<<<(E_DT + 255) / 256, 256, 0, stream>>>(ei_td + E_DT, E_DT, cnt_td);
    exscan_kernel<<<1, 1024, 0, stream>>>(cnt_gg, rp_gg, N_GENE);
    exscan_kernel<<<1, 1024, 0, stream>>>(cnt_dd, rp_dd, N_DRUG);
    exscan_kernel<<<1, 1024, 0, stream>>>(cnt_dt, rp_dt, N_GENE);
    exscan_kernel<<<1, 1024, 0, stream>>>(cnt_td, rp_td, N_DRUG);
    copy_int_kernel<<<(N_GENE + 255) / 256, 256, 0, stream>>>(rp_gg, pos_gg, N_GENE);
    copy_int_kernel<<<(N_DRUG + 255) / 256, 256, 0, stream>>>(rp_dd, pos_dd, N_DRUG);
    copy_int_kernel<<<(N_GENE + 255) / 256, 256, 0, stream>>>(rp_dt, pos_dt, N_GENE);
    copy_int_kernel<<<(N_DRUG + 255) / 256, 256, 0, stream>>>(rp_td, pos_td, N_DRUG);
    fill_csr_kernel<<<(E_GG + 255) / 256, 256, 0, stream>>>(ei_gg, ei_gg + E_GG, E_GG, pos_gg, col_gg);
    fill_csr_kernel<<<(E_DD + 255) / 256, 256, 0, stream>>>(ei_dd, ei_dd + E_DD, E_DD, pos_dd, col_dd);
    fill_csr_kernel<<<(E_DT + 255) / 256, 256, 0, stream>>>(ei_dt, ei_dt + E_DT, E_DT, pos_dt, col_dt);
    fill_csr_kernel<<<(E_DT + 255) / 256, 256, 0, stream>>>(ei_td, ei_td + E_DT, E_DT, pos_td, col_td);
    dinv_kernel<<<(N_GENE + 255) / 256, 256, 0, stream>>>(cnt_gg, dinv_g, N_GENE);
    dinv_kernel<<<(N_DRUG + 255) / 256, 256, 0, stream>>>(cnt_dd, dinv_d, N_DRUG);

    // ---- one conv: dropout+cast -> castT(W) -> tiled MFMA GEMM(bf16 out) -> fused agg ----
    auto run_conv = [&](const float* X, int M, int K, const float* W, const float* bias,
                        int h, const uint32_t* key, const int* rp, const int* col,
                        const float* dinvv, int n_dst, float* dest, int addmode) {
        int n = M * K;
        cast_mask_kernel<<<(n / 4 + 255) / 256, 256, 0, stream>>>(X, Am, key[0], key[1], n);
        castT_kernel<<<(K * h + 255) / 256, 256, 0, stream>>>(W, Wt, K, h);
        dim3 g((M + 63) / 64, h / 64);
        mfma_tile_kernel<<<g, 256, 0, stream>>>(Am, Wt, XWb, M, K, h);
        int blocks = (n_dst + 3) / 4;
        if (h == 256)
            agg_kernel<4><<<blocks, 256, 0, stream>>>(XWb, rp, col, dinvv, bias, dest, n_dst, addmode);
        else
            agg_kernel<2><<<blocks, 256, 0, stream>>>(XWb, rp, col, dinvv, bias, dest, n_dst, addmode);
    };

    // ---- layer 0 ----
    run_conv(gene, N_GENE, D_GENE, W0gg, b0gg, H0, dk[0], rp_gg, col_gg, dinv_g, N_GENE, xg1, 0);
    run_conv(drug, N_DRUG, D_DRUG, W0dt, b0dt, H0, dk[2], rp_dt, col_dt, nullptr, N_GENE, xg1, 1);
    run_conv(drug, N_DRUG, D_DRUG, W0dd, b0dd, H0, dk[1], rp_dd, col_dd, dinv_d, N_DRUG, xd1, 0);
    run_conv(gene, N_GENE, D_GENE, W0td, b0td, H0, dk[3], rp_td, col_td, nullptr, N_DRUG, xd1, 1);

    // ---- layer 1 -> d_out (genes then drugs) ----
    float* og = (float*)d_out;
    float* od = og + (size_t)N_GENE * H1;
    run_conv(xg1, N_GENE, H0, W1gg, b1gg, H1, dk[4], rp_gg, col_gg, dinv_g, N_GENE, og, 0);
    run_conv(xd1, N_DRUG, H0, W1dt, b1dt, H1, dk[6], rp_dt, col_dt, nullptr, N_GENE, og, 1);
    run_conv(xd1, N_DRUG, H0, W1dd, b1dd, H1, dk[5], rp_dd, col_dd, dinv_d, N_DRUG, od, 0);
    run_conv(xg1, N_GENE, H0, W1td, b1td, H1, dk[7], rp_td, col_td, nullptr, N_DRUG, od, 1);
}

// Round 5
// 625.839 us; speedup vs baseline: 2.3588x; 1.1749x over previous
//
#include <hip/hip_runtime.h>
#include <stdint.h>

#define N_GENE 20000
#define N_DRUG 3000
#define D_GENE 1024
#define D_DRUG 512
#define H0 256
#define H1 128
#define E_GG 600000
#define E_DD 120000
#define E_DT 150000

typedef __attribute__((ext_vector_type(8))) short bf16x8;
typedef __attribute__((ext_vector_type(4))) float f32x4;

// ---------------- Threefry-2x32 (JAX-compatible, 20 rounds) ----------------
__host__ __device__ inline uint32_t rotl32(uint32_t x, int d) {
    return (x << d) | (x >> (32 - d));
}

__host__ __device__ inline void tf2x32(uint32_t k0, uint32_t k1, uint32_t x0, uint32_t x1,
                                       uint32_t& o0, uint32_t& o1) {
    uint32_t ks2 = k0 ^ k1 ^ 0x1BD11BDAu;
    x0 += k0; x1 += k1;
#define TFR(r) { x0 += x1; x1 = rotl32(x1, r); x1 ^= x0; }
    TFR(13) TFR(15) TFR(26) TFR(6)
    x0 += k1; x1 += ks2 + 1u;
    TFR(17) TFR(29) TFR(16) TFR(24)
    x0 += ks2; x1 += k0 + 2u;
    TFR(13) TFR(15) TFR(26) TFR(6)
    x0 += k0; x1 += k1 + 3u;
    TFR(17) TFR(29) TFR(16) TFR(24)
    x0 += k1; x1 += ks2 + 4u;
    TFR(13) TFR(15) TFR(26) TFR(6)
    x0 += ks2; x1 += k0 + 5u;
#undef TFR
    o0 = x0; o1 = x1;
}

__device__ inline short f2bf(float f) {  // round-to-nearest-even bf16
    uint32_t u = __float_as_uint(f);
    uint32_t r = (u + 0x7FFFu + ((u >> 16) & 1u)) >> 16;
    return (short)r;
}
__device__ inline float bf_lo(uint32_t u) { return __uint_as_float(u << 16); }
__device__ inline float bf_hi(uint32_t u) { return __uint_as_float(u & 0xFFFF0000u); }

// fused dropout (partitionable threefry) + fp32->bf16 cast; 4 elems/thread
__global__ void cast_mask_kernel(const float* __restrict__ X, short* __restrict__ Y,
                                 uint32_t k0, uint32_t k1, int n) {
    int j = (blockIdx.x * 256 + threadIdx.x) * 4;
    if (j >= n) return;
    float4 x = *(const float4*)(X + j);
    short o[4];
    float xv[4] = {x.x, x.y, x.z, x.w};
#pragma unroll
    for (int i = 0; i < 4; i++) {
        uint32_t a, b;
        tf2x32(k0, k1, 0u, (uint32_t)(j + i), a, b);
        uint32_t bits = a ^ b;
        float u = __uint_as_float((bits >> 9) | 0x3F800000u) - 1.0f;
        o[i] = (u < 0.8f) ? f2bf(xv[i] * 1.25f) : (short)0;
    }
    *(short4*)(Y + j) = make_short4(o[0], o[1], o[2], o[3]);
}

// W[K,N] fp32 -> Wt[N,K] bf16
__global__ void castT_kernel(const float* __restrict__ W, short* __restrict__ Wt, int K, int N) {
    int idx = blockIdx.x * 256 + threadIdx.x;
    if (idx >= K * N) return;
    int n = idx / K, k = idx - n * K;
    Wt[idx] = f2bf(W[(size_t)k * N + n]);
}

// ---------------- LDS-tiled MFMA bf16 GEMM, bf16 output, optional row-scale ----------------
// C[M,N](bf16) = rowscale[r] * (A[M,K](bf16) @ Bt[N,K](bf16)^T), fp32 accum.
#define LDP 72
__global__ __launch_bounds__(256) void mfma_tile_kernel(
    const short* __restrict__ A, const short* __restrict__ Bt,
    short* __restrict__ C, const float* __restrict__ rowscale, int M, int K, int N) {
    __shared__ short As[64 * LDP];
    __shared__ short Bs[64 * LDP];
    int tid = threadIdx.x;
    int lane = tid & 63;
    int w = tid >> 6;
    int m = lane & 15, kb = lane >> 4;
    int m0w = (w >> 1) * 32, n0w = (w & 1) * 32;
    int gm = blockIdx.x * 64, gn = blockIdx.y * 64;

    int flat0 = tid, flat1 = tid + 256;
    int ar0 = flat0 >> 3, ac0 = (flat0 & 7) * 8;
    int ar1 = flat1 >> 3, ac1 = (flat1 & 7) * 8;
    int agr0 = min(gm + ar0, M - 1), agr1 = min(gm + ar1, M - 1);
    const short* pa0 = A + (size_t)agr0 * K + ac0;
    const short* pa1 = A + (size_t)agr1 * K + ac1;
    const short* pb0 = Bt + (size_t)(gn + ar0) * K + ac0;
    const short* pb1 = Bt + (size_t)(gn + ar1) * K + ac1;

    f32x4 acc[2][2];
#pragma unroll
    for (int i = 0; i < 2; i++)
#pragma unroll
        for (int j = 0; j < 2; j++) acc[i][j] = (f32x4){0.f, 0.f, 0.f, 0.f};

    uint4 ra0 = *(const uint4*)pa0;
    uint4 ra1 = *(const uint4*)pa1;
    uint4 rb0 = *(const uint4*)pb0;
    uint4 rb1 = *(const uint4*)pb1;

    int nt = K >> 6;
    for (int t = 0; t < nt; ++t) {
        __syncthreads();
        *(uint4*)&As[ar0 * LDP + ac0] = ra0;
        *(uint4*)&As[ar1 * LDP + ac1] = ra1;
        *(uint4*)&Bs[ar0 * LDP + ac0] = rb0;
        *(uint4*)&Bs[ar1 * LDP + ac1] = rb1;
        __syncthreads();
        if (t + 1 < nt) {
            int kt = (t + 1) << 6;
            ra0 = *(const uint4*)(pa0 + kt);
            ra1 = *(const uint4*)(pa1 + kt);
            rb0 = *(const uint4*)(pb0 + kt);
            rb1 = *(const uint4*)(pb1 + kt);
        }
#pragma unroll
        for (int ks = 0; ks < 2; ++ks) {
            bf16x8 a0 = *(const bf16x8*)&As[(m0w + m) * LDP + ks * 32 + kb * 8];
            bf16x8 a1 = *(const bf16x8*)&As[(m0w + 16 + m) * LDP + ks * 32 + kb * 8];
            bf16x8 b0 = *(const bf16x8*)&Bs[(n0w + m) * LDP + ks * 32 + kb * 8];
            bf16x8 b1 = *(const bf16x8*)&Bs[(n0w + 16 + m) * LDP + ks * 32 + kb * 8];
            acc[0][0] = __builtin_amdgcn_mfma_f32_16x16x32_bf16(a0, b0, acc[0][0], 0, 0, 0);
            acc[0][1] = __builtin_amdgcn_mfma_f32_16x16x32_bf16(a0, b1, acc[0][1], 0, 0, 0);
            acc[1][0] = __builtin_amdgcn_mfma_f32_16x16x32_bf16(a1, b0, acc[1][0], 0, 0, 0);
            acc[1][1] = __builtin_amdgcn_mfma_f32_16x16x32_bf16(a1, b1, acc[1][1], 0, 0, 0);
        }
    }
    // C/D layout: col = lane&15 (=m), row = kb*4 + j
#pragma unroll
    for (int mf = 0; mf < 2; ++mf)
#pragma unroll
        for (int j = 0; j < 4; ++j) {
            int r = gm + m0w + mf * 16 + kb * 4 + j;
            if (r < M) {
                float s = rowscale ? rowscale[r] : 1.0f;
#pragma unroll
                for (int nf = 0; nf < 2; ++nf)
                    C[(size_t)r * N + gn + n0w + nf * 16 + m] = f2bf(acc[mf][nf][j] * s);
            }
        }
}

// ---------------- CSR build ----------------
__global__ void count_dst_kernel(const int* __restrict__ dst, int E, int* cnt) {
    int e = blockIdx.x * 256 + threadIdx.x;
    if (e < E) atomicAdd(&cnt[dst[e]], 1);
}

__global__ void exscan_kernel(const int* __restrict__ cnt, int* __restrict__ rowptr, int n) {
    __shared__ int buf[1024];
    __shared__ int carry_s;
    int tid = threadIdx.x;
    if (tid == 0) carry_s = 0;
    __syncthreads();
    for (int base = 0; base < n; base += 1024) {
        int i = base + tid;
        int v = (i < n) ? cnt[i] : 0;
        buf[tid] = v;
        __syncthreads();
        for (int off = 1; off < 1024; off <<= 1) {
            int t = (tid >= off) ? buf[tid - off] : 0;
            __syncthreads();
            if (tid >= off) buf[tid] += t;
            __syncthreads();
        }
        int incl = buf[tid];
        int c = carry_s;
        __syncthreads();
        if (i < n) rowptr[i] = c + incl - v;
        if (tid == 1023) carry_s = c + buf[1023];
        __syncthreads();
    }
    if (tid == 0) rowptr[n] = carry_s;
}

__global__ void copy_int_kernel(const int* __restrict__ a, int* __restrict__ b, int n) {
    int i = blockIdx.x * 256 + threadIdx.x;
    if (i < n) b[i] = a[i];
}

__global__ void fill_csr_kernel(const int* __restrict__ src, const int* __restrict__ dst, int E,
                                int* pos, int* __restrict__ col) {
    int e = blockIdx.x * 256 + threadIdx.x;
    if (e < E) {
        int p = atomicAdd(&pos[dst[e]], 1);
        col[p] = src[e];
    }
}

__global__ void dinv_kernel(const int* __restrict__ cnt, float* __restrict__ dinv, int n) {
    int i = blockIdx.x * 256 + threadIdx.x;
    if (i < n) dinv[i] = 1.0f / sqrtf((float)cnt[i] + 1.0f);
}

// ---------------- fused aggregate (bf16 gather, 8-edge batch) + bias + relu + l2norm ----------------
// XWb rows pre-scaled by dinv[src] when NORM. lane owns features [lane*F, lane*F+F).
template <int F, bool NORM>
__global__ __launch_bounds__(256) void agg_kernel(
    const short* __restrict__ XWb, const int* __restrict__ rowptr, const int* __restrict__ col,
    const float* __restrict__ dinv, const float* __restrict__ bias,
    float* __restrict__ out, int n_dst, int addmode) {
    const int h = 64 * F;
    int lane = threadIdx.x & 63;
    int row = blockIdx.x * 4 + (threadIdx.x >> 6);
    if (row >= n_dst) return;
    int c0 = lane * F;
    float acc[F];
#pragma unroll
    for (int i = 0; i < F; i++) acc[i] = 0.f;

    int s0 = rowptr[row], s1 = rowptr[row + 1];
    if (NORM) {  // self loop: own (pre-scaled) row
        if constexpr (F == 4) {
            uint2 u = *(const uint2*)(XWb + (size_t)row * h + c0);
            acc[0] += bf_lo(u.x); acc[1] += bf_hi(u.x);
            acc[2] += bf_lo(u.y); acc[3] += bf_hi(u.y);
        } else {
            uint32_t u = *(const uint32_t*)(XWb + (size_t)row * h + c0);
            acc[0] += bf_lo(u); acc[1] += bf_hi(u);
        }
    }
    int p = s0;
    for (; p + 8 <= s1; p += 8) {  // 8 gathers in flight
        int c[8];
#pragma unroll
        for (int i = 0; i < 8; i++) c[i] = col[p + i];
        if constexpr (F == 4) {
            uint2 g[8];
#pragma unroll
            for (int i = 0; i < 8; i++) g[i] = *(const uint2*)(XWb + (size_t)c[i] * h + c0);
#pragma unroll
            for (int i = 0; i < 8; i++) {
                acc[0] += bf_lo(g[i].x); acc[1] += bf_hi(g[i].x);
                acc[2] += bf_lo(g[i].y); acc[3] += bf_hi(g[i].y);
            }
        } else {
            uint32_t g[8];
#pragma unroll
            for (int i = 0; i < 8; i++) g[i] = *(const uint32_t*)(XWb + (size_t)c[i] * h + c0);
#pragma unroll
            for (int i = 0; i < 8; i++) { acc[0] += bf_lo(g[i]); acc[1] += bf_hi(g[i]); }
        }
    }
    for (; p < s1; p++) {
        int s = col[p];
        if constexpr (F == 4) {
            uint2 u = *(const uint2*)(XWb + (size_t)s * h + c0);
            acc[0] += bf_lo(u.x); acc[1] += bf_hi(u.x);
            acc[2] += bf_lo(u.y); acc[3] += bf_hi(u.y);
        } else {
            uint32_t u = *(const uint32_t*)(XWb + (size_t)s * h + c0);
            acc[0] += bf_lo(u); acc[1] += bf_hi(u);
        }
    }

    float mul = NORM ? dinv[row] : 1.0f;
    float ss = 0.f;
#pragma unroll
    for (int i = 0; i < F; i++) {
        float v = acc[i] * mul + bias[c0 + i];
        v = fmaxf(v, 0.f);
        acc[i] = v;
        ss += v * v;
    }
#pragma unroll
    for (int off = 32; off >= 1; off >>= 1) ss += __shfl_xor(ss, off, 64);
    float scale = 1.0f / fmaxf(sqrtf(ss), 1e-12f);
    float* orow = out + (size_t)row * h + c0;
    if constexpr (F == 4) {
        float4 st = make_float4(acc[0] * scale, acc[1] * scale, acc[2] * scale, acc[3] * scale);
        if (addmode) {
            float4 old = *(const float4*)orow;
            st.x += old.x; st.y += old.y; st.z += old.z; st.w += old.w;
        }
        *(float4*)orow = st;
    } else {
        float2 st = make_float2(acc[0] * scale, acc[1] * scale);
        if (addmode) {
            float2 old = *(const float2*)orow;
            st.x += old.x; st.y += old.y;
        }
        *(float2*)orow = st;
    }
}

// ---------------- host ----------------
extern "C" void kernel_launch(void* const* d_in, const int* in_sizes, int n_in,
                              void* d_out, int out_size, void* d_ws, size_t ws_size,
                              hipStream_t stream) {
    const float* gene = (const float*)d_in[0];
    const float* drug = (const float*)d_in[1];
    const int* ei_gg = (const int*)d_in[2];
    const int* ei_dd = (const int*)d_in[3];
    const int* ei_dt = (const int*)d_in[4];
    const int* ei_td = (const int*)d_in[5];
    const float* W0gg = (const float*)d_in[6];  const float* b0gg = (const float*)d_in[7];
    const float* W0dd = (const float*)d_in[8];  const float* b0dd = (const float*)d_in[9];
    const float* W0dt = (const float*)d_in[10]; const float* b0dt = (const float*)d_in[11];
    const float* W0td = (const float*)d_in[12]; const float* b0td = (const float*)d_in[13];
    const float* W1gg = (const float*)d_in[14]; const float* b1gg = (const float*)d_in[15];
    const float* W1dd = (const float*)d_in[16]; const float* b1dd = (const float*)d_in[17];
    const float* W1dt = (const float*)d_in[18]; const float* b1dt = (const float*)d_in[19];
    const float* W1td = (const float*)d_in[20]; const float* b1td = (const float*)d_in[21];

    uint32_t dk[8][2];
    for (uint32_t i = 0; i < 8; i++) tf2x32(0u, 42u, 0u, i, dk[i][0], dk[i][1]);

    char* p = (char*)d_ws;
    auto take = [&](size_t bytes) -> void* {
        void* r = (void*)p;
        p += (bytes + 255) & ~(size_t)255;
        return r;
    };
    short* XWb  = (short*)take(sizeof(short) * (size_t)N_GENE * H0);
    float* xg1  = (float*)take(sizeof(float) * (size_t)N_GENE * H0);
    float* xd1  = (float*)take(sizeof(float) * (size_t)N_DRUG * H0);
    short* Am   = (short*)take(sizeof(short) * (size_t)N_GENE * D_GENE);
    short* Wt   = (short*)take(sizeof(short) * (size_t)D_GENE * H0);
    float* dinv_g = (float*)take(sizeof(float) * N_GENE);
    float* dinv_d = (float*)take(sizeof(float) * N_DRUG);
    int* cnt_gg = (int*)take(4 * N_GENE); int* rp_gg = (int*)take(4 * (N_GENE + 1));
    int* pos_gg = (int*)take(4 * N_GENE); int* col_gg = (int*)take(4 * E_GG);
    int* cnt_dd = (int*)take(4 * N_DRUG); int* rp_dd = (int*)take(4 * (N_DRUG + 1));
    int* pos_dd = (int*)take(4 * N_DRUG); int* col_dd = (int*)take(4 * E_DD);
    int* cnt_dt = (int*)take(4 * N_GENE); int* rp_dt = (int*)take(4 * (N_GENE + 1));
    int* pos_dt = (int*)take(4 * N_GENE); int* col_dt = (int*)take(4 * E_DT);
    int* cnt_td = (int*)take(4 * N_DRUG); int* rp_td = (int*)take(4 * (N_DRUG + 1));
    int* pos_td = (int*)take(4 * N_DRUG); int* col_td = (int*)take(4 * E_DT);

    // ---- CSR build (same graphs both layers) ----
    hipMemsetAsync(cnt_gg, 0, 4 * N_GENE, stream);
    hipMemsetAsync(cnt_dd, 0, 4 * N_DRUG, stream);
    hipMemsetAsync(cnt_dt, 0, 4 * N_GENE, stream);
    hipMemsetAsync(cnt_td, 0, 4 * N_DRUG, stream);
    count_dst_kernel<<<(E_GG + 255) / 256, 256, 0, stream>>>(ei_gg + E_GG, E_GG, cnt_gg);
    count_dst_kernel<<<(E_DD + 255) / 256, 256, 0, stream>>>(ei_dd + E_DD, E_DD, cnt_dd);
    count_dst_kernel<<<(E_DT + 255) / 256, 256, 0, stream>>>(ei_dt + E_DT, E_DT, cnt_dt);
    count_dst_kernel<<<(E_DT + 255) / 256, 256, 0, stream>>>(ei_td + E_DT, E_DT, cnt_td);
    exscan_kernel<<<1, 1024, 0, stream>>>(cnt_gg, rp_gg, N_GENE);
    exscan_kernel<<<1, 1024, 0, stream>>>(cnt_dd, rp_dd, N_DRUG);
    exscan_kernel<<<1, 1024, 0, stream>>>(cnt_dt, rp_dt, N_GENE);
    exscan_kernel<<<1, 1024, 0, stream>>>(cnt_td, rp_td, N_DRUG);
    copy_int_kernel<<<(N_GENE + 255) / 256, 256, 0, stream>>>(rp_gg, pos_gg, N_GENE);
    copy_int_kernel<<<(N_DRUG + 255) / 256, 256, 0, stream>>>(rp_dd, pos_dd, N_DRUG);
    copy_int_kernel<<<(N_GENE + 255) / 256, 256, 0, stream>>>(rp_dt, pos_dt, N_GENE);
    copy_int_kernel<<<(N_DRUG + 255) / 256, 256, 0, stream>>>(rp_td, pos_td, N_DRUG);
    fill_csr_kernel<<<(E_GG + 255) / 256, 256, 0, stream>>>(ei_gg, ei_gg + E_GG, E_GG, pos_gg, col_gg);
    fill_csr_kernel<<<(E_DD + 255) / 256, 256, 0, stream>>>(ei_dd, ei_dd + E_DD, E_DD, pos_dd, col_dd);
    fill_csr_kernel<<<(E_DT + 255) / 256, 256, 0, stream>>>(ei_dt, ei_dt + E_DT, E_DT, pos_dt, col_dt);
    fill_csr_kernel<<<(E_DT + 255) / 256, 256, 0, stream>>>(ei_td, ei_td + E_DT, E_DT, pos_td, col_td);
    dinv_kernel<<<(N_GENE + 255) / 256, 256, 0, stream>>>(cnt_gg, dinv_g, N_GENE);
    dinv_kernel<<<(N_DRUG + 255) / 256, 256, 0, stream>>>(cnt_dd, dinv_d, N_DRUG);

    // ---- one conv: dropout+cast -> castT(W) -> MFMA GEMM(bf16 out, rowscale) -> agg ----
    auto run_conv = [&](const float* X, int M, int K, const float* W, const float* bias,
                        int h, const uint32_t* key, const int* rp, const int* col,
                        const float* dinvv, int n_dst, float* dest, int addmode) {
        int n = M * K;
        cast_mask_kernel<<<(n / 4 + 255) / 256, 256, 0, stream>>>(X, Am, key[0], key[1], n);
        castT_kernel<<<(K * h + 255) / 256, 256, 0, stream>>>(W, Wt, K, h);
        dim3 g((M + 63) / 64, h / 64);
        mfma_tile_kernel<<<g, 256, 0, stream>>>(Am, Wt, XWb, dinvv, M, K, h);
        int blocks = (n_dst + 3) / 4;
        if (h == 256) {
            if (dinvv)
                agg_kernel<4, true><<<blocks, 256, 0, stream>>>(XWb, rp, col, dinvv, bias, dest, n_dst, addmode);
            else
                agg_kernel<4, false><<<blocks, 256, 0, stream>>>(XWb, rp, col, dinvv, bias, dest, n_dst, addmode);
        } else {
            if (dinvv)
                agg_kernel<2, true><<<blocks, 256, 0, stream>>>(XWb, rp, col, dinvv, bias, dest, n_dst, addmode);
            else
                agg_kernel<2, false><<<blocks, 256, 0, stream>>>(XWb, rp, col, dinvv, bias, dest, n_dst, addmode);
        }
    };

    // ---- layer 0 ----
    run_conv(gene, N_GENE, D_GENE, W0gg, b0gg, H0, dk[0], rp_gg, col_gg, dinv_g, N_GENE, xg1, 0);
    run_conv(drug, N_DRUG, D_DRUG, W0dt, b0dt, H0, dk[2], rp_dt, col_dt, nullptr, N_GENE, xg1, 1);
    run_conv(drug, N_DRUG, D_DRUG, W0dd, b0dd, H0, dk[1], rp_dd, col_dd, dinv_d, N_DRUG, xd1, 0);
    run_conv(gene, N_GENE, D_GENE, W0td, b0td, H0, dk[3], rp_td, col_td, nullptr, N_DRUG, xd1, 1);

    // ---- layer 1 -> d_out (genes then drugs) ----
    float* og = (float*)d_out;
    float* od = og + (size_t)N_GENE * H1;
    run_conv(xg1, N_GENE, H0, W1gg, b1gg, H1, dk[4], rp_gg, col_gg, dinv_g, N_GENE, og, 0);
    run_conv(xd1, N_DRUG, H0, W1dt, b1dt, H1, dk[6], rp_dt, col_dt, nullptr, N_GENE, og, 1);
    run_conv(xd1, N_DRUG, H0, W1dd, b1dd, H1, dk[5], rp_dd, col_dd, dinv_d, N_DRUG, od, 0);
    run_conv(xg1, N_GENE, H0, W1td, b1td, H1, dk[7], rp_td, col_td, nullptr, N_DRUG, od, 1);
}

// Round 6
// 464.725 us; speedup vs baseline: 3.1766x; 1.3467x over previous
//
#include <hip/hip_runtime.h>
#include <stdint.h>

#define N_GENE 20000
#define N_DRUG 3000
#define D_GENE 1024
#define D_DRUG 512
#define H0 256
#define H1 128
#define E_GG 600000
#define E_DD 120000
#define E_DT 150000

typedef __attribute__((ext_vector_type(8))) short bf16x8;
typedef __attribute__((ext_vector_type(4))) float f32x4;

// ---------------- Threefry-2x32 (JAX partitionable semantics) ----------------
__host__ __device__ inline uint32_t rotl32(uint32_t x, int d) {
    return (x << d) | (x >> (32 - d));
}

__host__ __device__ inline void tf2x32(uint32_t k0, uint32_t k1, uint32_t x0, uint32_t x1,
                                       uint32_t& o0, uint32_t& o1) {
    uint32_t ks2 = k0 ^ k1 ^ 0x1BD11BDAu;
    x0 += k0; x1 += k1;
#define TFR(r) { x0 += x1; x1 = rotl32(x1, r); x1 ^= x0; }
    TFR(13) TFR(15) TFR(26) TFR(6)
    x0 += k1; x1 += ks2 + 1u;
    TFR(17) TFR(29) TFR(16) TFR(24)
    x0 += ks2; x1 += k0 + 2u;
    TFR(13) TFR(15) TFR(26) TFR(6)
    x0 += k0; x1 += k1 + 3u;
    TFR(17) TFR(29) TFR(16) TFR(24)
    x0 += k1; x1 += ks2 + 4u;
    TFR(13) TFR(15) TFR(26) TFR(6)
    x0 += ks2; x1 += k0 + 5u;
#undef TFR
    o0 = x0; o1 = x1;
}

__device__ inline short f2bf(float f) {  // round-to-nearest-even bf16
    uint32_t u = __float_as_uint(f);
    uint32_t r = (u + 0x7FFFu + ((u >> 16) & 1u)) >> 16;
    return (short)r;
}
__device__ inline float bf_lo(uint32_t u) { return __uint_as_float(u << 16); }
__device__ inline float bf_hi(uint32_t u) { return __uint_as_float(u & 0xFFFF0000u); }

// ---------------- fused 4-region dropout+cast, 8 elems/thread ----------------
// keep iff (bits>>9) < 6710887  (== u < 0.8f exactly)
struct Cast4P {
    unsigned c0, c1, c2, c3;  // cumulative elem counts (R0..R3); R0,R1 from Xg; R2,R3 from Xd
    uint32_t k0a, k1a, k0b, k1b, k0c, k1c, k0d, k1d;
};
__global__ __launch_bounds__(256) void cast4_kernel(const float* __restrict__ Xg,
                                                    const float* __restrict__ Xd,
                                                    short* __restrict__ Am, Cast4P P) {
    unsigned j = (blockIdx.x * 256u + threadIdx.x) * 8u;
    if (j >= P.c3) return;
    unsigned base; uint32_t k0, k1; const float* X;
    if (j >= P.c2)      { base = P.c2; k0 = P.k0d; k1 = P.k1d; X = Xd; }
    else if (j >= P.c1) { base = P.c1; k0 = P.k0c; k1 = P.k1c; X = Xd; }
    else if (j >= P.c0) { base = P.c0; k0 = P.k0b; k1 = P.k1b; X = Xg; }
    else                { base = 0u;   k0 = P.k0a; k1 = P.k1a; X = Xg; }
    unsigned local = j - base;
    float4 xa = *(const float4*)(X + local);
    float4 xb = *(const float4*)(X + local + 4);
    float xv[8] = {xa.x, xa.y, xa.z, xa.w, xb.x, xb.y, xb.z, xb.w};
    union { short s[8]; uint4 u; } st;
#pragma unroll
    for (int i = 0; i < 8; i++) {
        uint32_t a, b;
        tf2x32(k0, k1, 0u, local + (unsigned)i, a, b);
        uint32_t bits = a ^ b;
        st.s[i] = ((bits >> 9) < 6710887u) ? f2bf(xv[i] * 1.25f) : (short)0;
    }
    *(uint4*)(Am + j) = st.u;
}

// ---------------- fused 4-region W[K,N] -> Wt[N,K] bf16 ----------------
struct CastT4P {
    unsigned c0, c1, c2, c3;
    int lgK0, lgK1, lgK2, lgK3;
    int N;
};
__global__ __launch_bounds__(256) void castT4_kernel(
    const float* __restrict__ W0, const float* __restrict__ W1,
    const float* __restrict__ W2, const float* __restrict__ W3,
    short* __restrict__ Wt, CastT4P P) {
    unsigned idx = blockIdx.x * 256u + threadIdx.x;
    if (idx >= P.c3) return;
    unsigned base; const float* W; int lgK;
    if (idx >= P.c2)      { base = P.c2; W = W3; lgK = P.lgK3; }
    else if (idx >= P.c1) { base = P.c1; W = W2; lgK = P.lgK2; }
    else if (idx >= P.c0) { base = P.c0; W = W1; lgK = P.lgK1; }
    else                  { base = 0u;   W = W0; lgK = P.lgK0; }
    unsigned local = idx - base;
    unsigned n = local >> lgK, k = local & ((1u << lgK) - 1u);
    Wt[idx] = f2bf(W[(size_t)k * P.N + n]);
}

// ---------------- fused 4-desc LDS-tiled MFMA bf16 GEMM ----------------
// C = rowscale ? rowscale[r]*(A@Bt^T) : A@Bt^T, bf16 out, fp32 accum
struct GDesc { unsigned aoff, boff, coff; const float* rs; int M, K, mb0; };
#define LDP 72
__global__ __launch_bounds__(256) void gemm4_kernel(
    const short* __restrict__ Ab, const short* __restrict__ Wb, short* __restrict__ Cb,
    GDesc d0, GDesc d1, GDesc d2, GDesc d3, int N) {
    __shared__ short As[64 * LDP];
    __shared__ short Bs[64 * LDP];
    GDesc d;
    int bx = blockIdx.x;
    if (bx >= d3.mb0) d = d3;
    else if (bx >= d2.mb0) d = d2;
    else if (bx >= d1.mb0) d = d1;
    else d = d0;
    bx -= d.mb0;
    const short* A = Ab + d.aoff;
    const short* Bt = Wb + d.boff;
    short* C = Cb + d.coff;
    const int M = d.M, K = d.K;

    int tid = threadIdx.x;
    int lane = tid & 63;
    int w = tid >> 6;
    int m = lane & 15, kb = lane >> 4;
    int m0w = (w >> 1) * 32, n0w = (w & 1) * 32;
    int gm = bx * 64, gn = blockIdx.y * 64;

    int flat0 = tid, flat1 = tid + 256;
    int ar0 = flat0 >> 3, ac0 = (flat0 & 7) * 8;
    int ar1 = flat1 >> 3, ac1 = (flat1 & 7) * 8;
    int agr0 = min(gm + ar0, M - 1), agr1 = min(gm + ar1, M - 1);
    const short* pa0 = A + (size_t)agr0 * K + ac0;
    const short* pa1 = A + (size_t)agr1 * K + ac1;
    const short* pb0 = Bt + (size_t)(gn + ar0) * K + ac0;
    const short* pb1 = Bt + (size_t)(gn + ar1) * K + ac1;

    f32x4 acc[2][2];
#pragma unroll
    for (int i = 0; i < 2; i++)
#pragma unroll
        for (int j = 0; j < 2; j++) acc[i][j] = (f32x4){0.f, 0.f, 0.f, 0.f};

    uint4 ra0 = *(const uint4*)pa0;
    uint4 ra1 = *(const uint4*)pa1;
    uint4 rb0 = *(const uint4*)pb0;
    uint4 rb1 = *(const uint4*)pb1;

    int nt = K >> 6;
    for (int t = 0; t < nt; ++t) {
        __syncthreads();
        *(uint4*)&As[ar0 * LDP + ac0] = ra0;
        *(uint4*)&As[ar1 * LDP + ac1] = ra1;
        *(uint4*)&Bs[ar0 * LDP + ac0] = rb0;
        *(uint4*)&Bs[ar1 * LDP + ac1] = rb1;
        __syncthreads();
        if (t + 1 < nt) {
            int kt = (t + 1) << 6;
            ra0 = *(const uint4*)(pa0 + kt);
            ra1 = *(const uint4*)(pa1 + kt);
            rb0 = *(const uint4*)(pb0 + kt);
            rb1 = *(const uint4*)(pb1 + kt);
        }
#pragma unroll
        for (int ks = 0; ks < 2; ++ks) {
            bf16x8 a0 = *(const bf16x8*)&As[(m0w + m) * LDP + ks * 32 + kb * 8];
            bf16x8 a1 = *(const bf16x8*)&As[(m0w + 16 + m) * LDP + ks * 32 + kb * 8];
            bf16x8 b0 = *(const bf16x8*)&Bs[(n0w + m) * LDP + ks * 32 + kb * 8];
            bf16x8 b1 = *(const bf16x8*)&Bs[(n0w + 16 + m) * LDP + ks * 32 + kb * 8];
            acc[0][0] = __builtin_amdgcn_mfma_f32_16x16x32_bf16(a0, b0, acc[0][0], 0, 0, 0);
            acc[0][1] = __builtin_amdgcn_mfma_f32_16x16x32_bf16(a0, b1, acc[0][1], 0, 0, 0);
            acc[1][0] = __builtin_amdgcn_mfma_f32_16x16x32_bf16(a1, b0, acc[1][0], 0, 0, 0);
            acc[1][1] = __builtin_amdgcn_mfma_f32_16x16x32_bf16(a1, b1, acc[1][1], 0, 0, 0);
        }
    }
#pragma unroll
    for (int mf = 0; mf < 2; ++mf)
#pragma unroll
        for (int j = 0; j < 4; ++j) {
            int r = gm + m0w + mf * 16 + kb * 4 + j;
            if (r < M) {
                float s = d.rs ? d.rs[r] : 1.0f;
#pragma unroll
                for (int nf = 0; nf < 2; ++nf)
                    C[(size_t)r * N + gn + n0w + nf * 16 + m] = f2bf(acc[mf][nf][j] * s);
            }
        }
}

// ---------------- fused CSR build (4 graphs) ----------------
// region order: gg, dd, dt, td
// cnt/pos offsets: 0, 20000, 23000, 43000  (total 46000)
// col offsets: 0, 600000, 720000, 870000  (total 1020000)
#define CUM_E0 600000u
#define CUM_E1 720000u
#define CUM_E2 870000u
#define CUM_E3 1020000u

__global__ void count4_kernel(const int* __restrict__ gg, const int* __restrict__ dd,
                              const int* __restrict__ dt, const int* __restrict__ td,
                              int* __restrict__ cnt) {
    unsigned e = blockIdx.x * 256u + threadIdx.x;
    if (e >= CUM_E3) return;
    const int* dsts; unsigned base, noff;
    if (e >= CUM_E2)      { dsts = td + E_DT; base = CUM_E2; noff = 43000; }
    else if (e >= CUM_E1) { dsts = dt + E_DT; base = CUM_E1; noff = 23000; }
    else if (e >= CUM_E0) { dsts = dd + E_DD; base = CUM_E0; noff = 20000; }
    else                  { dsts = gg + E_GG; base = 0;      noff = 0; }
    atomicAdd(&cnt[noff + dsts[e - base]], 1);
}

// 4 blocks; block b scans its region
__global__ void scan4_kernel(const int* __restrict__ cnt,
                             int* __restrict__ rp0, int* __restrict__ rp1,
                             int* __restrict__ rp2, int* __restrict__ rp3) {
    __shared__ int buf[1024];
    __shared__ int carry_s;
    const int ns[4]   = {20000, 3000, 20000, 3000};
    const int offs[4] = {0, 20000, 23000, 43000};
    int b = blockIdx.x;
    int n = ns[b];
    const int* c = cnt + offs[b];
    int* rowptr = (b == 0) ? rp0 : (b == 1) ? rp1 : (b == 2) ? rp2 : rp3;
    int tid = threadIdx.x;
    if (tid == 0) carry_s = 0;
    __syncthreads();
    for (int base = 0; base < n; base += 1024) {
        int i = base + tid;
        int v = (i < n) ? c[i] : 0;
        buf[tid] = v;
        __syncthreads();
        for (int off = 1; off < 1024; off <<= 1) {
            int t = (tid >= off) ? buf[tid - off] : 0;
            __syncthreads();
            if (tid >= off) buf[tid] += t;
            __syncthreads();
        }
        int incl = buf[tid];
        int cc = carry_s;
        __syncthreads();
        if (i < n) rowptr[i] = cc + incl - v;
        if (tid == 1023) carry_s = cc + buf[1023];
        __syncthreads();
    }
    if (tid == 0) rowptr[n] = carry_s;
}

__global__ void copy4_kernel(const int* __restrict__ rp0, const int* __restrict__ rp1,
                             const int* __restrict__ rp2, const int* __restrict__ rp3,
                             int* __restrict__ pos) {
    unsigned i = blockIdx.x * 256u + threadIdx.x;
    if (i >= 46000u) return;
    int v;
    if (i >= 43000u) v = rp3[i - 43000u];
    else if (i >= 23000u) v = rp2[i - 23000u];
    else if (i >= 20000u) v = rp1[i - 20000u];
    else v = rp0[i];
    pos[i] = v;
}

__global__ void fill4_kernel(const int* __restrict__ gg, const int* __restrict__ dd,
                             const int* __restrict__ dt, const int* __restrict__ td,
                             int* __restrict__ pos, int* __restrict__ col) {
    unsigned e = blockIdx.x * 256u + threadIdx.x;
    if (e >= CUM_E3) return;
    const int* ei; unsigned base, noff, coff; int E;
    if (e >= CUM_E2)      { ei = td; base = CUM_E2; noff = 43000; coff = 870000; E = E_DT; }
    else if (e >= CUM_E1) { ei = dt; base = CUM_E1; noff = 23000; coff = 720000; E = E_DT; }
    else if (e >= CUM_E0) { ei = dd; base = CUM_E0; noff = 20000; coff = 600000; E = E_DD; }
    else                  { ei = gg; base = 0;      noff = 0;     coff = 0;      E = E_GG; }
    unsigned local = e - base;
    int src = ei[local], dst = ei[E + local];
    int p = atomicAdd(&pos[noff + dst], 1);
    col[coff + p] = src;
}

__global__ void dinv2_kernel(const int* __restrict__ cnt, float* __restrict__ dinv_g,
                             float* __restrict__ dinv_d) {
    unsigned i = blockIdx.x * 256u + threadIdx.x;
    if (i >= 23000u) return;
    if (i < 20000u) dinv_g[i] = 1.0f / sqrtf((float)cnt[i] + 1.0f);
    else dinv_d[i - 20000u] = 1.0f / sqrtf((float)cnt[i] + 1.0f);
}

// ---------------- fused dual aggregate + bias + relu + l2norm + sum ----------------
// out[row] = l2n(relu(dinv[row]*sum_a XWa + ba)) + l2n(relu(sum_b XWb + bb))
// XWa rows pre-scaled by dinv[src] in GEMM epilogue. lane owns [lane*F, lane*F+F).
template <int F>
__global__ __launch_bounds__(256) void agg2_kernel(
    const short* __restrict__ XWa, const int* __restrict__ rpa, const int* __restrict__ cola,
    const float* __restrict__ dinv, const float* __restrict__ ba,
    const short* __restrict__ XWb2, const int* __restrict__ rpb, const int* __restrict__ colb,
    const float* __restrict__ bb, float* __restrict__ out, int n_dst) {
    const int h = 64 * F;
    int lane = threadIdx.x & 63;
    int row = blockIdx.x * 4 + (threadIdx.x >> 6);
    if (row >= n_dst) return;
    int c0 = lane * F;
    float acc[F], va[F];

    // ---- norm side (self loop + edges) ----
#pragma unroll
    for (int i = 0; i < F; i++) acc[i] = 0.f;
    {
        if constexpr (F == 4) {
            uint2 u = *(const uint2*)(XWa + (size_t)row * h + c0);
            acc[0] += bf_lo(u.x); acc[1] += bf_hi(u.x);
            acc[2] += bf_lo(u.y); acc[3] += bf_hi(u.y);
        } else {
            uint32_t u = *(const uint32_t*)(XWa + (size_t)row * h + c0);
            acc[0] += bf_lo(u); acc[1] += bf_hi(u);
        }
        int s0 = rpa[row], s1 = rpa[row + 1];
        int p = s0;
        for (; p + 8 <= s1; p += 8) {
            int c[8];
#pragma unroll
            for (int i = 0; i < 8; i++) c[i] = cola[p + i];
            if constexpr (F == 4) {
                uint2 g[8];
#pragma unroll
                for (int i = 0; i < 8; i++) g[i] = *(const uint2*)(XWa + (size_t)c[i] * h + c0);
#pragma unroll
                for (int i = 0; i < 8; i++) {
                    acc[0] += bf_lo(g[i].x); acc[1] += bf_hi(g[i].x);
                    acc[2] += bf_lo(g[i].y); acc[3] += bf_hi(g[i].y);
                }
            } else {
                uint32_t g[8];
#pragma unroll
                for (int i = 0; i < 8; i++) g[i] = *(const uint32_t*)(XWa + (size_t)c[i] * h + c0);
#pragma unroll
                for (int i = 0; i < 8; i++) { acc[0] += bf_lo(g[i]); acc[1] += bf_hi(g[i]); }
            }
        }
        for (; p < s1; p++) {
            int s = cola[p];
            if constexpr (F == 4) {
                uint2 u = *(const uint2*)(XWa + (size_t)s * h + c0);
                acc[0] += bf_lo(u.x); acc[1] += bf_hi(u.x);
                acc[2] += bf_lo(u.y); acc[3] += bf_hi(u.y);
            } else {
                uint32_t u = *(const uint32_t*)(XWa + (size_t)s * h + c0);
                acc[0] += bf_lo(u); acc[1] += bf_hi(u);
            }
        }
    }
    float mul = dinv[row];
    float ssa = 0.f;
#pragma unroll
    for (int i = 0; i < F; i++) {
        float v = fmaxf(acc[i] * mul + ba[c0 + i], 0.f);
        va[i] = v;
        ssa += v * v;
    }

    // ---- plain side ----
#pragma unroll
    for (int i = 0; i < F; i++) acc[i] = 0.f;
    {
        int s0 = rpb[row], s1 = rpb[row + 1];
        int p = s0;
        for (; p + 8 <= s1; p += 8) {
            int c[8];
#pragma unroll
            for (int i = 0; i < 8; i++) c[i] = colb[p + i];
            if constexpr (F == 4) {
                uint2 g[8];
#pragma unroll
                for (int i = 0; i < 8; i++) g[i] = *(const uint2*)(XWb2 + (size_t)c[i] * h + c0);
#pragma unroll
                for (int i = 0; i < 8; i++) {
                    acc[0] += bf_lo(g[i].x); acc[1] += bf_hi(g[i].x);
                    acc[2] += bf_lo(g[i].y); acc[3] += bf_hi(g[i].y);
                }
            } else {
                uint32_t g[8];
#pragma unroll
                for (int i = 0; i < 8; i++) g[i] = *(const uint32_t*)(XWb2 + (size_t)c[i] * h + c0);
#pragma unroll
                for (int i = 0; i < 8; i++) { acc[0] += bf_lo(g[i]); acc[1] += bf_hi(g[i]); }
            }
        }
        for (; p < s1; p++) {
            int s = colb[p];
            if constexpr (F == 4) {
                uint2 u = *(const uint2*)(XWb2 + (size_t)s * h + c0);
                acc[0] += bf_lo(u.x); acc[1] += bf_hi(u.x);
                acc[2] += bf_lo(u.y); acc[3] += bf_hi(u.y);
            } else {
                uint32_t u = *(const uint32_t*)(XWb2 + (size_t)s * h + c0);
                acc[0] += bf_lo(u); acc[1] += bf_hi(u);
            }
        }
    }
    float ssb = 0.f;
#pragma unroll
    for (int i = 0; i < F; i++) {
        float v = fmaxf(acc[i] + bb[c0 + i], 0.f);
        acc[i] = v;
        ssb += v * v;
    }

#pragma unroll
    for (int off = 32; off >= 1; off >>= 1) {
        ssa += __shfl_xor(ssa, off, 64);
        ssb += __shfl_xor(ssb, off, 64);
    }
    float sa = 1.0f / fmaxf(sqrtf(ssa), 1e-12f);
    float sb = 1.0f / fmaxf(sqrtf(ssb), 1e-12f);
    float* orow = out + (size_t)row * h + c0;
    if constexpr (F == 4) {
        *(float4*)orow = make_float4(va[0] * sa + acc[0] * sb, va[1] * sa + acc[1] * sb,
                                     va[2] * sa + acc[2] * sb, va[3] * sa + acc[3] * sb);
    } else {
        *(float2*)orow = make_float2(va[0] * sa + acc[0] * sb, va[1] * sa + acc[1] * sb);
    }
}

// ---------------- host ----------------
extern "C" void kernel_launch(void* const* d_in, const int* in_sizes, int n_in,
                              void* d_out, int out_size, void* d_ws, size_t ws_size,
                              hipStream_t stream) {
    const float* gene = (const float*)d_in[0];
    const float* drug = (const float*)d_in[1];
    const int* ei_gg = (const int*)d_in[2];
    const int* ei_dd = (const int*)d_in[3];
    const int* ei_dt = (const int*)d_in[4];
    const int* ei_td = (const int*)d_in[5];
    const float* W0gg = (const float*)d_in[6];  const float* b0gg = (const float*)d_in[7];
    const float* W0dd = (const float*)d_in[8];  const float* b0dd = (const float*)d_in[9];
    const float* W0dt = (const float*)d_in[10]; const float* b0dt = (const float*)d_in[11];
    const float* W0td = (const float*)d_in[12]; const float* b0td = (const float*)d_in[13];
    const float* W1gg = (const float*)d_in[14]; const float* b1gg = (const float*)d_in[15];
    const float* W1dd = (const float*)d_in[16]; const float* b1dd = (const float*)d_in[17];
    const float* W1dt = (const float*)d_in[18]; const float* b1dt = (const float*)d_in[19];
    const float* W1td = (const float*)d_in[20]; const float* b1td = (const float*)d_in[21];

    uint32_t dk[8][2];
    for (uint32_t i = 0; i < 8; i++) tf2x32(0u, 42u, 0u, i, dk[i][0], dk[i][1]);

    char* p = (char*)d_ws;
    auto take = [&](size_t bytes) -> void* {
        void* r = (void*)p;
        p += (bytes + 255) & ~(size_t)255;
        return r;
    };
    // A regions (desc order gg, td, dd, dt): layer0 sizes 20.48M, 20.48M, 1.536M, 1.536M
    short* Am   = (short*)take(sizeof(short) * 44032000ULL);
    // XW regions (desc order): gg 5.12M, td 5.12M, dd 0.768M, dt 0.768M elems
    short* XW   = (short*)take(sizeof(short) * 11776000ULL);
    short* Wt   = (short*)take(sizeof(short) * 786432ULL);
    float* xg1  = (float*)take(sizeof(float) * (size_t)N_GENE * H0);
    float* xd1  = (float*)take(sizeof(float) * (size_t)N_DRUG * H0);
    float* dinv_g = (float*)take(sizeof(float) * N_GENE);
    float* dinv_d = (float*)take(sizeof(float) * N_DRUG);
    int* cnt = (int*)take(4 * 46000);
    int* pos = (int*)take(4 * 46000);
    int* col = (int*)take(4 * 1020000);
    int* rp_gg = (int*)take(4 * (N_GENE + 1));
    int* rp_dd = (int*)take(4 * (N_DRUG + 1));
    int* rp_dt = (int*)take(4 * (N_GENE + 1));
    int* rp_td = (int*)take(4 * (N_DRUG + 1));

    // ---- CSR build: 6 dispatches ----
    hipMemsetAsync(cnt, 0, 4 * 46000, stream);
    count4_kernel<<<(1020000 + 255) / 256, 256, 0, stream>>>(ei_gg, ei_dd, ei_dt, ei_td, cnt);
    scan4_kernel<<<4, 1024, 0, stream>>>(cnt, rp_gg, rp_dd, rp_dt, rp_td);
    copy4_kernel<<<(46000 + 255) / 256, 256, 0, stream>>>(rp_gg, rp_dd, rp_dt, rp_td, pos);
    fill4_kernel<<<(1020000 + 255) / 256, 256, 0, stream>>>(ei_gg, ei_dd, ei_dt, ei_td, pos, col);
    dinv2_kernel<<<(23000 + 255) / 256, 256, 0, stream>>>(cnt, dinv_g, dinv_d);

    const int* col_gg = col;
    const int* col_dd = col + 600000;
    const int* col_dt = col + 720000;
    const int* col_td = col + 870000;

    // ================= layer 0 =================
    {
        // cast: regions R0=gg(dk0,gene) R1=td(dk3,gene) R2=dd(dk1,drug) R3=dt(dk2,drug)
        Cast4P cp = {20480000u, 40960000u, 42496000u, 44032000u,
                     dk[0][0], dk[0][1], dk[3][0], dk[3][1],
                     dk[1][0], dk[1][1], dk[2][0], dk[2][1]};
        cast4_kernel<<<(44032000 / 8 + 255) / 256, 256, 0, stream>>>(gene, drug, Am, cp);
        // weights: gg(1024x256) td(1024x256) dd(512x256) dt(512x256)
        CastT4P tp = {262144u, 524288u, 655360u, 786432u, 10, 10, 9, 9, H0};
        castT4_kernel<<<(786432 + 255) / 256, 256, 0, stream>>>(W0gg, W0td, W0dd, W0dt, Wt, tp);
        GDesc g0 = {0u,         0u,       0u,         dinv_g, N_GENE, 1024, 0};
        GDesc g1 = {20480000u,  262144u,  5120000u,   nullptr, N_GENE, 1024, 313};
        GDesc g2 = {40960000u,  524288u,  10240000u,  dinv_d, N_DRUG, 512, 626};
        GDesc g3 = {42496000u,  655360u,  11008000u,  nullptr, N_DRUG, 512, 673};
        gemm4_kernel<<<dim3(720, H0 / 64), 256, 0, stream>>>(Am, Wt, XW, g0, g1, g2, g3, H0);
        // gene dst: norm=gg(XW+0), plain=dt(XW+11008000)
        agg2_kernel<4><<<(N_GENE + 3) / 4, 256, 0, stream>>>(
            XW, rp_gg, col_gg, dinv_g, b0gg,
            XW + 11008000, rp_dt, col_dt, b0dt, xg1, N_GENE);
        // drug dst: norm=dd(XW+10240000), plain=td(XW+5120000)
        agg2_kernel<4><<<(N_DRUG + 3) / 4, 256, 0, stream>>>(
            XW + 10240000, rp_dd, col_dd, dinv_d, b0dd,
            XW + 5120000, rp_td, col_td, b0td, xd1, N_DRUG);
    }

    // ================= layer 1 =================
    {
        Cast4P cp = {5120000u, 10240000u, 11008000u, 11776000u,
                     dk[4][0], dk[4][1], dk[7][0], dk[7][1],
                     dk[5][0], dk[5][1], dk[6][0], dk[6][1]};
        cast4_kernel<<<(11776000 / 8 + 255) / 256, 256, 0, stream>>>(xg1, xd1, Am, cp);
        CastT4P tp = {32768u, 65536u, 98304u, 131072u, 8, 8, 8, 8, H1};
        castT4_kernel<<<(131072 + 255) / 256, 256, 0, stream>>>(W1gg, W1td, W1dd, W1dt, Wt, tp);
        GDesc g0 = {0u,         0u,      0u,         dinv_g, N_GENE, 256, 0};
        GDesc g1 = {5120000u,   32768u,  5120000u,   nullptr, N_GENE, 256, 313};
        GDesc g2 = {10240000u,  65536u,  10240000u,  dinv_d, N_DRUG, 256, 626};
        GDesc g3 = {11008000u,  98304u,  11008000u,  nullptr, N_DRUG, 256, 673};
        gemm4_kernel<<<dim3(720, H1 / 64), 256, 0, stream>>>(Am, Wt, XW, g0, g1, g2, g3, H1);
        float* og = (float*)d_out;
        float* od = og + (size_t)N_GENE * H1;
        agg2_kernel<2><<<(N_GENE + 3) / 4, 256, 0, stream>>>(
            XW, rp_gg, col_gg, dinv_g, b1gg,
            XW + 11008000, rp_dt, col_dt, b1dt, og, N_GENE);
        agg2_kernel<2><<<(N_DRUG + 3) / 4, 256, 0, stream>>>(
            XW + 10240000, rp_dd, col_dd, dinv_d, b1dd,
            XW + 5120000, rp_td, col_td, b1td, od, N_DRUG);
    }
}

// Round 7
// 421.265 us; speedup vs baseline: 3.5043x; 1.1032x over previous
//
#include <hip/hip_runtime.h>
#include <stdint.h>

#define N_GENE 20000
#define N_DRUG 3000
#define D_GENE 1024
#define D_DRUG 512
#define H0 256
#define H1 128
#define E_GG 600000
#define E_DD 120000
#define E_DT 150000

typedef __attribute__((ext_vector_type(8))) short bf16x8;
typedef __attribute__((ext_vector_type(4))) float f32x4;

// ---------------- Threefry-2x32 (JAX partitionable semantics) ----------------
__host__ __device__ inline uint32_t rotl32(uint32_t x, int d) {
#ifdef __HIP_DEVICE_COMPILE__
    return __builtin_amdgcn_alignbit(x, x, 32 - d);  // v_alignbit_b32: 1-inst rotate
#else
    return (x << d) | (x >> (32 - d));
#endif
}

__host__ __device__ inline void tf2x32(uint32_t k0, uint32_t k1, uint32_t x0, uint32_t x1,
                                       uint32_t& o0, uint32_t& o1) {
    uint32_t ks2 = k0 ^ k1 ^ 0x1BD11BDAu;
    x0 += k0; x1 += k1;
#define TFR(r) { x0 += x1; x1 = rotl32(x1, r); x1 ^= x0; }
    TFR(13) TFR(15) TFR(26) TFR(6)
    x0 += k1; x1 += ks2 + 1u;
    TFR(17) TFR(29) TFR(16) TFR(24)
    x0 += ks2; x1 += k0 + 2u;
    TFR(13) TFR(15) TFR(26) TFR(6)
    x0 += k0; x1 += k1 + 3u;
    TFR(17) TFR(29) TFR(16) TFR(24)
    x0 += k1; x1 += ks2 + 4u;
    TFR(13) TFR(15) TFR(26) TFR(6)
    x0 += ks2; x1 += k0 + 5u;
#undef TFR
    o0 = x0; o1 = x1;
}

__device__ inline short f2bf(float f) {  // round-to-nearest-even bf16
    uint32_t u = __float_as_uint(f);
    uint32_t r = (u + 0x7FFFu + ((u >> 16) & 1u)) >> 16;
    return (short)r;
}
__device__ inline float bf_lo(uint32_t u) { return __uint_as_float(u << 16); }
__device__ inline float bf_hi(uint32_t u) { return __uint_as_float(u & 0xFFFF0000u); }

// region constants (order gg, dd, dt, td)
#define CUM_E0 600000u
#define CUM_E1 720000u
#define CUM_E2 870000u
#define CUM_E3 1020000u

// ---------------- fused 4-region dropout+cast (+ optional edge count) ----------------
// keep iff (bits>>9) < 6710887  (== u < 0.8f exactly)
struct Cast4P {
    unsigned c0, c1, c2, c3;  // cumulative elem counts; R0,R1 from Xg; R2,R3 from Xd
    uint32_t k0a, k1a, k0b, k1b, k0c, k1c, k0d, k1d;
};
__global__ __launch_bounds__(256) void cast4_kernel(
    const float* __restrict__ Xg, const float* __restrict__ Xd,
    short* __restrict__ Am, Cast4P P, int castBlocks,
    const int* __restrict__ gg, const int* __restrict__ dd,
    const int* __restrict__ dt, const int* __restrict__ td, int* __restrict__ cnt) {
    int bx = blockIdx.x;
    if (bx >= castBlocks) {  // trailing blocks: edge-count histogram (overlaps cast tail)
        unsigned e = (unsigned)(bx - castBlocks) * 256u + threadIdx.x;
        if (e >= CUM_E3) return;
        const int* dsts; unsigned base, noff;
        if (e >= CUM_E2)      { dsts = td + E_DT; base = CUM_E2; noff = 43000; }
        else if (e >= CUM_E1) { dsts = dt + E_DT; base = CUM_E1; noff = 23000; }
        else if (e >= CUM_E0) { dsts = dd + E_DD; base = CUM_E0; noff = 20000; }
        else                  { dsts = gg + E_GG; base = 0;      noff = 0; }
        atomicAdd(&cnt[noff + dsts[e - base]], 1);
        return;
    }
    unsigned j = ((unsigned)bx * 256u + threadIdx.x) * 8u;
    if (j >= P.c3) return;
    unsigned base; uint32_t k0, k1; const float* X;
    if (j >= P.c2)      { base = P.c2; k0 = P.k0d; k1 = P.k1d; X = Xd; }
    else if (j >= P.c1) { base = P.c1; k0 = P.k0c; k1 = P.k1c; X = Xd; }
    else if (j >= P.c0) { base = P.c0; k0 = P.k0b; k1 = P.k1b; X = Xg; }
    else                { base = 0u;   k0 = P.k0a; k1 = P.k1a; X = Xg; }
    unsigned local = j - base;
    float4 xa = *(const float4*)(X + local);
    float4 xb = *(const float4*)(X + local + 4);
    float xv[8] = {xa.x, xa.y, xa.z, xa.w, xb.x, xb.y, xb.z, xb.w};
    union { short s[8]; uint4 u; } st;
#pragma unroll
    for (int i = 0; i < 8; i++) {
        uint32_t a, b;
        tf2x32(k0, k1, 0u, local + (unsigned)i, a, b);
        uint32_t bits = a ^ b;
        st.s[i] = ((bits >> 9) < 6710887u) ? f2bf(xv[i] * 1.25f) : (short)0;
    }
    *(uint4*)(Am + j) = st.u;
}

// ---------------- parallel scan over cnt[46000] ----------------
__global__ __launch_bounds__(1024) void scan_p1(const int* __restrict__ cnt,
                                                int* __restrict__ tmp, int* __restrict__ bsum) {
    __shared__ int buf[1024];
    int tid = threadIdx.x;
    int i = blockIdx.x * 1024 + tid;
    int v = (i < 46000) ? cnt[i] : 0;
    buf[tid] = v;
    __syncthreads();
    for (int off = 1; off < 1024; off <<= 1) {
        int t = (tid >= off) ? buf[tid - off] : 0;
        __syncthreads();
        buf[tid] += t;
        __syncthreads();
    }
    if (i < 46000) tmp[i] = buf[tid];
    if (tid == 1023) bsum[blockIdx.x] = buf[1023];
}

__global__ void scan_p2(int* __restrict__ bsum) {  // exclusive scan of 45 block sums (1 wave)
    int lane = threadIdx.x;
    int v = (lane < 45) ? bsum[lane] : 0;
    int orig = v;
    for (int off = 1; off < 64; off <<= 1) {
        int t = __shfl_up(v, off, 64);
        if (lane >= off) v += t;
    }
    if (lane < 45) bsum[lane] = v - orig;
}

// apply block offsets -> global exclusive scan; write rowptr_all + pos + dinv
__global__ __launch_bounds__(1024) void scan_p3(const int* __restrict__ cnt,
                                                const int* __restrict__ tmp,
                                                const int* __restrict__ bsum,
                                                int* __restrict__ rpall, int* __restrict__ pos,
                                                float* __restrict__ dinv_g,
                                                float* __restrict__ dinv_d) {
    int i = blockIdx.x * 1024 + threadIdx.x;
    if (i < 46000) {
        int g = tmp[i] - cnt[i] + bsum[blockIdx.x];
        rpall[i] = g;
        pos[i] = g;
        if (i < 20000) dinv_g[i] = 1.0f / sqrtf((float)cnt[i] + 1.0f);
        else if (i < 23000) dinv_d[i - 20000] = 1.0f / sqrtf((float)cnt[i] + 1.0f);
    }
    if (i == 0) rpall[46000] = (int)CUM_E3;
}

// ---------------- fused CSR fill + weight transpose/cast ----------------
struct CastT4P {
    unsigned c0, c1, c2, c3;
    int lgK0, lgK1, lgK2, lgK3;
    int N;
};
__global__ __launch_bounds__(256) void fillcastT_kernel(
    const int* __restrict__ gg, const int* __restrict__ dd,
    const int* __restrict__ dt, const int* __restrict__ td,
    int* __restrict__ pos, int* __restrict__ col,
    const float* __restrict__ W0, const float* __restrict__ W1,
    const float* __restrict__ W2, const float* __restrict__ W3,
    short* __restrict__ Wt, CastT4P P, int fillBlocks) {
    int bx = blockIdx.x;
    if (bx < fillBlocks) {  // CSR fill (pos holds global offsets; col needs no region offset)
        unsigned e = (unsigned)bx * 256u + threadIdx.x;
        if (e >= CUM_E3) return;
        const int* ei; unsigned base, noff; int E;
        if (e >= CUM_E2)      { ei = td; base = CUM_E2; noff = 43000; E = E_DT; }
        else if (e >= CUM_E1) { ei = dt; base = CUM_E1; noff = 23000; E = E_DT; }
        else if (e >= CUM_E0) { ei = dd; base = CUM_E0; noff = 20000; E = E_DD; }
        else                  { ei = gg; base = 0;      noff = 0;     E = E_GG; }
        unsigned local = e - base;
        int src = ei[local], dst = ei[E + local];
        int p = atomicAdd(&pos[noff + dst], 1);
        col[p] = src;
        return;
    }
    unsigned idx = (unsigned)(bx - fillBlocks) * 256u + threadIdx.x;
    if (idx >= P.c3) return;
    unsigned base; const float* W; int lgK;
    if (idx >= P.c2)      { base = P.c2; W = W3; lgK = P.lgK3; }
    else if (idx >= P.c1) { base = P.c1; W = W2; lgK = P.lgK2; }
    else if (idx >= P.c0) { base = P.c0; W = W1; lgK = P.lgK1; }
    else                  { base = 0u;   W = W0; lgK = P.lgK0; }
    unsigned local = idx - base;
    unsigned n = local >> lgK, k = local & ((1u << lgK) - 1u);
    Wt[idx] = f2bf(W[(size_t)k * P.N + n]);
}

// standalone castT for layer 1
__global__ __launch_bounds__(256) void castT4_kernel(
    const float* __restrict__ W0, const float* __restrict__ W1,
    const float* __restrict__ W2, const float* __restrict__ W3,
    short* __restrict__ Wt, CastT4P P) {
    unsigned idx = blockIdx.x * 256u + threadIdx.x;
    if (idx >= P.c3) return;
    unsigned base; const float* W; int lgK;
    if (idx >= P.c2)      { base = P.c2; W = W3; lgK = P.lgK3; }
    else if (idx >= P.c1) { base = P.c1; W = W2; lgK = P.lgK2; }
    else if (idx >= P.c0) { base = P.c0; W = W1; lgK = P.lgK1; }
    else                  { base = 0u;   W = W0; lgK = P.lgK0; }
    unsigned local = idx - base;
    unsigned n = local >> lgK, k = local & ((1u << lgK) - 1u);
    Wt[idx] = f2bf(W[(size_t)k * P.N + n]);
}

// ---------------- fused 4-desc LDS-tiled MFMA bf16 GEMM ----------------
struct GDesc { unsigned aoff, boff, coff; const float* rs; int M, K, mb0; };
#define LDP 72
__global__ __launch_bounds__(256) void gemm4_kernel(
    const short* __restrict__ Ab, const short* __restrict__ Wb, short* __restrict__ Cb,
    GDesc d0, GDesc d1, GDesc d2, GDesc d3, int N) {
    __shared__ short As[64 * LDP];
    __shared__ short Bs[64 * LDP];
    GDesc d;
    int bx = blockIdx.x;
    if (bx >= d3.mb0) d = d3;
    else if (bx >= d2.mb0) d = d2;
    else if (bx >= d1.mb0) d = d1;
    else d = d0;
    bx -= d.mb0;
    const short* A = Ab + d.aoff;
    const short* Bt = Wb + d.boff;
    short* C = Cb + d.coff;
    const int M = d.M, K = d.K;

    int tid = threadIdx.x;
    int lane = tid & 63;
    int w = tid >> 6;
    int m = lane & 15, kb = lane >> 4;
    int m0w = (w >> 1) * 32, n0w = (w & 1) * 32;
    int gm = bx * 64, gn = blockIdx.y * 64;

    int flat0 = tid, flat1 = tid + 256;
    int ar0 = flat0 >> 3, ac0 = (flat0 & 7) * 8;
    int ar1 = flat1 >> 3, ac1 = (flat1 & 7) * 8;
    int agr0 = min(gm + ar0, M - 1), agr1 = min(gm + ar1, M - 1);
    const short* pa0 = A + (size_t)agr0 * K + ac0;
    const short* pa1 = A + (size_t)agr1 * K + ac1;
    const short* pb0 = Bt + (size_t)(gn + ar0) * K + ac0;
    const short* pb1 = Bt + (size_t)(gn + ar1) * K + ac1;

    f32x4 acc[2][2];
#pragma unroll
    for (int i = 0; i < 2; i++)
#pragma unroll
        for (int j = 0; j < 2; j++) acc[i][j] = (f32x4){0.f, 0.f, 0.f, 0.f};

    uint4 ra0 = *(const uint4*)pa0;
    uint4 ra1 = *(const uint4*)pa1;
    uint4 rb0 = *(const uint4*)pb0;
    uint4 rb1 = *(const uint4*)pb1;

    int nt = K >> 6;
    for (int t = 0; t < nt; ++t) {
        __syncthreads();
        *(uint4*)&As[ar0 * LDP + ac0] = ra0;
        *(uint4*)&As[ar1 * LDP + ac1] = ra1;
        *(uint4*)&Bs[ar0 * LDP + ac0] = rb0;
        *(uint4*)&Bs[ar1 * LDP + ac1] = rb1;
        __syncthreads();
        if (t + 1 < nt) {
            int kt = (t + 1) << 6;
            ra0 = *(const uint4*)(pa0 + kt);
            ra1 = *(const uint4*)(pa1 + kt);
            rb0 = *(const uint4*)(pb0 + kt);
            rb1 = *(const uint4*)(pb1 + kt);
        }
#pragma unroll
        for (int ks = 0; ks < 2; ++ks) {
            bf16x8 a0 = *(const bf16x8*)&As[(m0w + m) * LDP + ks * 32 + kb * 8];
            bf16x8 a1 = *(const bf16x8*)&As[(m0w + 16 + m) * LDP + ks * 32 + kb * 8];
            bf16x8 b0 = *(const bf16x8*)&Bs[(n0w + m) * LDP + ks * 32 + kb * 8];
            bf16x8 b1 = *(const bf16x8*)&Bs[(n0w + 16 + m) * LDP + ks * 32 + kb * 8];
            acc[0][0] = __builtin_amdgcn_mfma_f32_16x16x32_bf16(a0, b0, acc[0][0], 0, 0, 0);
            acc[0][1] = __builtin_amdgcn_mfma_f32_16x16x32_bf16(a0, b1, acc[0][1], 0, 0, 0);
            acc[1][0] = __builtin_amdgcn_mfma_f32_16x16x32_bf16(a1, b0, acc[1][0], 0, 0, 0);
            acc[1][1] = __builtin_amdgcn_mfma_f32_16x16x32_bf16(a1, b1, acc[1][1], 0, 0, 0);
        }
    }
#pragma unroll
    for (int mf = 0; mf < 2; ++mf)
#pragma unroll
        for (int j = 0; j < 4; ++j) {
            int r = gm + m0w + mf * 16 + kb * 4 + j;
            if (r < M) {
                float s = d.rs ? d.rs[r] : 1.0f;
#pragma unroll
                for (int nf = 0; nf < 2; ++nf)
                    C[(size_t)r * N + gn + n0w + nf * 16 + m] = f2bf(acc[mf][nf][j] * s);
            }
        }
}

// ---------------- fused dual aggregate + bias + relu + l2norm + sum ----------------
// rpa/rpb hold GLOBAL exclusive-scan values; col is the global column array.
template <int F>
__global__ __launch_bounds__(256) void agg2_kernel(
    const short* __restrict__ XWa, const int* __restrict__ rpa,
    const float* __restrict__ dinv, const float* __restrict__ ba,
    const short* __restrict__ XWb2, const int* __restrict__ rpb,
    const float* __restrict__ bb, const int* __restrict__ col,
    float* __restrict__ out, int n_dst) {
    const int h = 64 * F;
    int lane = threadIdx.x & 63;
    int row = blockIdx.x * 4 + (threadIdx.x >> 6);
    if (row >= n_dst) return;
    int c0 = lane * F;
    float acc[F], va[F];

    // ---- norm side (self loop + edges; rows pre-scaled by dinv[src]) ----
#pragma unroll
    for (int i = 0; i < F; i++) acc[i] = 0.f;
    {
        if constexpr (F == 4) {
            uint2 u = *(const uint2*)(XWa + (size_t)row * h + c0);
            acc[0] += bf_lo(u.x); acc[1] += bf_hi(u.x);
            acc[2] += bf_lo(u.y); acc[3] += bf_hi(u.y);
        } else {
            uint32_t u = *(const uint32_t*)(XWa + (size_t)row * h + c0);
            acc[0] += bf_lo(u); acc[1] += bf_hi(u);
        }
        int s0 = rpa[row], s1 = rpa[row + 1];
        int p = s0;
        for (; p + 8 <= s1; p += 8) {
            int c[8];
#pragma unroll
            for (int i = 0; i < 8; i++) c[i] = col[p + i];
            if constexpr (F == 4) {
                uint2 g[8];
#pragma unroll
                for (int i = 0; i < 8; i++) g[i] = *(const uint2*)(XWa + (size_t)c[i] * h + c0);
#pragma unroll
                for (int i = 0; i < 8; i++) {
                    acc[0] += bf_lo(g[i].x); acc[1] += bf_hi(g[i].x);
                    acc[2] += bf_lo(g[i].y); acc[3] += bf_hi(g[i].y);
                }
            } else {
                uint32_t g[8];
#pragma unroll
                for (int i = 0; i < 8; i++) g[i] = *(const uint32_t*)(XWa + (size_t)c[i] * h + c0);
#pragma unroll
                for (int i = 0; i < 8; i++) { acc[0] += bf_lo(g[i]); acc[1] += bf_hi(g[i]); }
            }
        }
        for (; p < s1; p++) {
            int s = col[p];
            if constexpr (F == 4) {
                uint2 u = *(const uint2*)(XWa + (size_t)s * h + c0);
                acc[0] += bf_lo(u.x); acc[1] += bf_hi(u.x);
                acc[2] += bf_lo(u.y); acc[3] += bf_hi(u.y);
            } else {
                uint32_t u = *(const uint32_t*)(XWa + (size_t)s * h + c0);
                acc[0] += bf_lo(u); acc[1] += bf_hi(u);
            }
        }
    }
    float mul = dinv[row];
    float ssa = 0.f;
#pragma unroll
    for (int i = 0; i < F; i++) {
        float v = fmaxf(acc[i] * mul + ba[c0 + i], 0.f);
        va[i] = v;
        ssa += v * v;
    }

    // ---- plain side ----
#pragma unroll
    for (int i = 0; i < F; i++) acc[i] = 0.f;
    {
        int s0 = rpb[row], s1 = rpb[row + 1];
        int p = s0;
        for (; p + 8 <= s1; p += 8) {
            int c[8];
#pragma unroll
            for (int i = 0; i < 8; i++) c[i] = col[p + i];
            if constexpr (F == 4) {
                uint2 g[8];
#pragma unroll
                for (int i = 0; i < 8; i++) g[i] = *(const uint2*)(XWb2 + (size_t)c[i] * h + c0);
#pragma unroll
                for (int i = 0; i < 8; i++) {
                    acc[0] += bf_lo(g[i].x); acc[1] += bf_hi(g[i].x);
                    acc[2] += bf_lo(g[i].y); acc[3] += bf_hi(g[i].y);
                }
            } else {
                uint32_t g[8];
#pragma unroll
                for (int i = 0; i < 8; i++) g[i] = *(const uint32_t*)(XWb2 + (size_t)c[i] * h + c0);
#pragma unroll
                for (int i = 0; i < 8; i++) { acc[0] += bf_lo(g[i]); acc[1] += bf_hi(g[i]); }
            }
        }
        for (; p < s1; p++) {
            int s = col[p];
            if constexpr (F == 4) {
                uint2 u = *(const uint2*)(XWb2 + (size_t)s * h + c0);
                acc[0] += bf_lo(u.x); acc[1] += bf_hi(u.x);
                acc[2] += bf_lo(u.y); acc[3] += bf_hi(u.y);
            } else {
                uint32_t u = *(const uint32_t*)(XWb2 + (size_t)s * h + c0);
                acc[0] += bf_lo(u); acc[1] += bf_hi(u);
            }
        }
    }
    float ssb = 0.f;
#pragma unroll
    for (int i = 0; i < F; i++) {
        float v = fmaxf(acc[i] + bb[c0 + i], 0.f);
        acc[i] = v;
        ssb += v * v;
    }

#pragma unroll
    for (int off = 32; off >= 1; off >>= 1) {
        ssa += __shfl_xor(ssa, off, 64);
        ssb += __shfl_xor(ssb, off, 64);
    }
    float sa = 1.0f / fmaxf(sqrtf(ssa), 1e-12f);
    float sb = 1.0f / fmaxf(sqrtf(ssb), 1e-12f);
    float* orow = out + (size_t)row * h + c0;
    if constexpr (F == 4) {
        *(float4*)orow = make_float4(va[0] * sa + acc[0] * sb, va[1] * sa + acc[1] * sb,
                                     va[2] * sa + acc[2] * sb, va[3] * sa + acc[3] * sb);
    } else {
        *(float2*)orow = make_float2(va[0] * sa + acc[0] * sb, va[1] * sa + acc[1] * sb);
    }
}

// ---------------- host ----------------
extern "C" void kernel_launch(void* const* d_in, const int* in_sizes, int n_in,
                              void* d_out, int out_size, void* d_ws, size_t ws_size,
                              hipStream_t stream) {
    const float* gene = (const float*)d_in[0];
    const float* drug = (const float*)d_in[1];
    const int* ei_gg = (const int*)d_in[2];
    const int* ei_dd = (const int*)d_in[3];
    const int* ei_dt = (const int*)d_in[4];
    const int* ei_td = (const int*)d_in[5];
    const float* W0gg = (const float*)d_in[6];  const float* b0gg = (const float*)d_in[7];
    const float* W0dd = (const float*)d_in[8];  const float* b0dd = (const float*)d_in[9];
    const float* W0dt = (const float*)d_in[10]; const float* b0dt = (const float*)d_in[11];
    const float* W0td = (const float*)d_in[12]; const float* b0td = (const float*)d_in[13];
    const float* W1gg = (const float*)d_in[14]; const float* b1gg = (const float*)d_in[15];
    const float* W1dd = (const float*)d_in[16]; const float* b1dd = (const float*)d_in[17];
    const float* W1dt = (const float*)d_in[18]; const float* b1dt = (const float*)d_in[19];
    const float* W1td = (const float*)d_in[20]; const float* b1td = (const float*)d_in[21];

    uint32_t dk[8][2];
    for (uint32_t i = 0; i < 8; i++) tf2x32(0u, 42u, 0u, i, dk[i][0], dk[i][1]);

    char* p = (char*)d_ws;
    auto take = [&](size_t bytes) -> void* {
        void* r = (void*)p;
        p += (bytes + 255) & ~(size_t)255;
        return r;
    };
    short* Am   = (short*)take(sizeof(short) * 44032000ULL);
    short* XW   = (short*)take(sizeof(short) * 11776000ULL);
    short* Wt   = (short*)take(sizeof(short) * 786432ULL);
    float* xg1  = (float*)take(sizeof(float) * (size_t)N_GENE * H0);
    float* xd1  = (float*)take(sizeof(float) * (size_t)N_DRUG * H0);
    float* dinv_g = (float*)take(sizeof(float) * N_GENE);
    float* dinv_d = (float*)take(sizeof(float) * N_DRUG);
    int* cnt   = (int*)take(4 * 46000);
    int* tmp   = (int*)take(4 * 46000);
    int* bsum  = (int*)take(4 * 64);
    int* pos   = (int*)take(4 * 46000);
    int* rpall = (int*)take(4 * 46001);
    int* col   = (int*)take(4 * 1020000);

    // region rowptr views (global exclusive-scan values; col is shared base)
    const int* rp_gg = rpall;
    const int* rp_dd = rpall + 20000;
    const int* rp_dt = rpall + 23000;
    const int* rp_td = rpall + 43000;

    hipMemsetAsync(cnt, 0, 4 * 46000, stream);

    // ================= layer 0 =================
    {
        // cast regions: R0=gg(dk0,gene) R1=td(dk3,gene) R2=dd(dk1,drug) R3=dt(dk2,drug)
        Cast4P cp = {20480000u, 40960000u, 42496000u, 44032000u,
                     dk[0][0], dk[0][1], dk[3][0], dk[3][1],
                     dk[1][0], dk[1][1], dk[2][0], dk[2][1]};
        int castBlocks = 44032000 / 8 / 256;                 // 21500
        int countBlocks = (1020000 + 255) / 256;             // 3985
        cast4_kernel<<<castBlocks + countBlocks, 256, 0, stream>>>(
            gene, drug, Am, cp, castBlocks, ei_gg, ei_dd, ei_dt, ei_td, cnt);
        scan_p1<<<45, 1024, 0, stream>>>(cnt, tmp, bsum);
        scan_p2<<<1, 64, 0, stream>>>(bsum);
        scan_p3<<<45, 1024, 0, stream>>>(cnt, tmp, bsum, rpall, pos, dinv_g, dinv_d);
        // fill + weight cast: gg(1024x256) td(1024x256) dd(512x256) dt(512x256)
        CastT4P tp = {262144u, 524288u, 655360u, 786432u, 10, 10, 9, 9, H0};
        int fillBlocks = (1020000 + 255) / 256;
        fillcastT_kernel<<<fillBlocks + (786432 + 255) / 256, 256, 0, stream>>>(
            ei_gg, ei_dd, ei_dt, ei_td, pos, col,
            W0gg, W0td, W0dd, W0dt, Wt, tp, fillBlocks);
        GDesc g0 = {0u,        0u,      0u,        dinv_g,  N_GENE, 1024, 0};
        GDesc g1 = {20480000u, 262144u, 5120000u,  nullptr, N_GENE, 1024, 313};
        GDesc g2 = {40960000u, 524288u, 10240000u, dinv_d,  N_DRUG, 512,  626};
        GDesc g3 = {42496000u, 655360u, 11008000u, nullptr, N_DRUG, 512,  673};
        gemm4_kernel<<<dim3(720, H0 / 64), 256, 0, stream>>>(Am, Wt, XW, g0, g1, g2, g3, H0);
        agg2_kernel<4><<<(N_GENE + 3) / 4, 256, 0, stream>>>(
            XW, rp_gg, dinv_g, b0gg, XW + 11008000, rp_dt, b0dt, col, xg1, N_GENE);
        agg2_kernel<4><<<(N_DRUG + 3) / 4, 256, 0, stream>>>(
            XW + 10240000, rp_dd, dinv_d, b0dd, XW + 5120000, rp_td, b0td, col, xd1, N_DRUG);
    }

    // ================= layer 1 =================
    {
        Cast4P cp = {5120000u, 10240000u, 11008000u, 11776000u,
                     dk[4][0], dk[4][1], dk[7][0], dk[7][1],
                     dk[5][0], dk[5][1], dk[6][0], dk[6][1]};
        int castBlocks = 11776000 / 8 / 256;  // 5750
        cast4_kernel<<<castBlocks, 256, 0, stream>>>(
            xg1, xd1, Am, cp, castBlocks, nullptr, nullptr, nullptr, nullptr, nullptr);
        CastT4P tp = {32768u, 65536u, 98304u, 131072u, 8, 8, 8, 8, H1};
        castT4_kernel<<<(131072 + 255) / 256, 256, 0, stream>>>(W1gg, W1td, W1dd, W1dt, Wt, tp);
        GDesc g0 = {0u,        0u,     0u,        dinv_g,  N_GENE, 256, 0};
        GDesc g1 = {5120000u,  32768u, 5120000u,  nullptr, N_GENE, 256, 313};
        GDesc g2 = {10240000u, 65536u, 10240000u, dinv_d,  N_DRUG, 256, 626};
        GDesc g3 = {11008000u, 98304u, 11008000u, nullptr, N_DRUG, 256, 673};
        gemm4_kernel<<<dim3(720, H1 / 64), 256, 0, stream>>>(Am, Wt, XW, g0, g1, g2, g3, H1);
        float* og = (float*)d_out;
        float* od = og + (size_t)N_GENE * H1;
        agg2_kernel<2><<<(N_GENE + 3) / 4, 256, 0, stream>>>(
            XW, rp_gg, dinv_g, b1gg, XW + 11008000, rp_dt, b1dt, col, og, N_GENE);
        agg2_kernel<2><<<(N_DRUG + 3) / 4, 256, 0, stream>>>(
            XW + 10240000, rp_dd, dinv_d, b1dd, XW + 5120000, rp_td, b1td, col, od, N_DRUG);
    }
}